// Round 13
// baseline (623.628 us; speedup 1.0000x reference)
//
#include <hip/hip_runtime.h>
#include <hip/hip_bf16.h>

#define NNODES 500000
#define NEDGES 8000000
#define NGRAPHS 512
#define NFEAT 128
#define NHID 128
#define NFILT 8
#define ODIM 64
#define BN_EPS 1e-5f
#define NBLK2 3907  // ceil(NNODES/128)
#define NBLK3 7813  // ceil(NNODES/64)  for k_bn
#define NBLK4 977   // ceil(NNODES/512) for k_pairs/k_ds1/k_ds2a (4 tiles/block)

typedef __attribute__((ext_vector_type(8))) short bf16x8;
typedef __attribute__((ext_vector_type(4))) float f32x4;
#define MFMA16(a, b, c) __builtin_amdgcn_mfma_f32_16x16x32_bf16(a, b, c, 0, 0, 0)

__device__ inline ushort f2bs(float f) {
  union { __hip_bfloat16 h; ushort u; } cv;
  cv.h = __float2bfloat16(f);
  return cv.u;
}

// ---- pack weights into MFMA A-frag layout + cnt[g] binary search (merged) ----
__global__ void k_pack(const float* __restrict__ g1W, const float* __restrict__ g2W,
                       const float* __restrict__ W1, const float* __restrict__ W0,
                       const int* __restrict__ batch,
                       ushort* __restrict__ pW1, ushort* __restrict__ pW2,
                       ushort* __restrict__ pW0, ushort* __restrict__ pW0p,
                       int* __restrict__ cnt) {
  int idx = blockIdx.x * 256 + threadIdx.x;
  if (idx < 4096) {
    int j = idx & 7, l = (idx >> 3) & 63, kb = (idx >> 9) & 1, ncb = idx >> 10;
    int k = kb * 32 + (l >> 4) * 8 + j, c = ncb * 16 + (l & 15);
    pW1[idx] = f2bs(g1W[k * 64 + c]);
  }
  if (idx < 8192) {
    int j = idx & 7, l = (idx >> 3) & 63, kb = (idx >> 9) & 1, ncb = idx >> 10;
    int k = kb * 32 + (l >> 4) * 8 + j, c = ncb * 16 + (l & 15);
    pW2[idx] = f2bs(g2W[k * 128 + c]);
  }
  if (idx < 16384) {
    int j = idx & 7, l = (idx >> 3) & 63, kb = (idx >> 9) & 3, ncb = idx >> 11;
    int k = kb * 32 + (l >> 4) * 8 + j, c = ncb * 16 + (l & 15);
    pW0[idx] = f2bs(W1[k * 128 + c]);
  }
  if (idx < 4096) {
    int j = idx & 7, l = (idx >> 3) & 63, ncb = idx >> 9;
    int k = (l >> 4) * 8 + j, c = ncb * 16 + (l & 15);
    pW0p[idx] = (k < 16) ? f2bs(W0[k * 64 + c]) : (ushort)0;
  }
  if (idx < NGRAPHS) {
    int g = idx;
    int lo0 = 0, hi0 = NNODES;
    while (lo0 < hi0) { int mid = (lo0 + hi0) >> 1; if (batch[mid] < g) lo0 = mid + 1; else hi0 = mid; }
    int lo1 = lo0, hi1 = NNODES;
    while (lo1 < hi1) { int mid = (lo1 + hi1) >> 1; if (batch[mid] < g + 1) lo1 = mid + 1; else hi1 = mid; }
    cnt[g] = lo1 - lo0;
  }
}

// ---- Kernel 1 (MFMA): fv16 = bf16( relu(x@W1+b1)@W2 + b2 )  [N,8] ----
__global__ __launch_bounds__(256) void k_filt(
    const float* __restrict__ x, const ushort* __restrict__ pW0,
    const float* __restrict__ b1, const float* __restrict__ W2,
    const float* __restrict__ b2, ushort* __restrict__ fv16) {
  __shared__ float w2s[128 * 12];
  const int t = threadIdx.x;
  for (int i = t; i < 1024; i += 256) {
    int c = i >> 3, f = i & 7;
    w2s[c * 12 + f] = W2[i];
  }
  __syncthreads();
  const int wv = t >> 6, l = t & 63;
  const int lr = l & 15, lg = l >> 4;
  const int n0 = blockIdx.x * 128 + wv * 32;
  if (n0 >= NNODES) return;

  union { uint4 u; bf16x8 b; } bf[2][4];
#pragma unroll
  for (int mt = 0; mt < 2; ++mt)
#pragma unroll
    for (int kb = 0; kb < 4; ++kb) {
      const float* src = &x[(size_t)(n0 + mt * 16 + lr) * 128 + kb * 32 + lg * 8];
      float v[8];
      *(float4*)&v[0] = *(const float4*)src;
      *(float4*)&v[4] = *(const float4*)(src + 4);
      ushort s[8];
#pragma unroll
      for (int e = 0; e < 8; ++e) s[e] = f2bs(v[e]);
      bf[mt][kb].u = *(uint4*)s;
    }

  float pf0[8], pf1[8];
#pragma unroll
  for (int f = 0; f < 8; ++f) { pf0[f] = 0.f; pf1[f] = 0.f; }

#pragma unroll
  for (int ncb = 0; ncb < 8; ++ncb) {
    union { uint4 u; bf16x8 b; } af[4];
#pragma unroll
    for (int kb = 0; kb < 4; ++kb)
      af[kb].u = *(const uint4*)&pW0[((ncb * 4 + kb) * 64 + l) * 8];
    f32x4 a0 = (f32x4){0.f, 0.f, 0.f, 0.f};
    f32x4 a1 = (f32x4){0.f, 0.f, 0.f, 0.f};
#pragma unroll
    for (int kb = 0; kb < 4; ++kb) {
      a0 = MFMA16(af[kb].b, bf[0][kb].b, a0);
      a1 = MFMA16(af[kb].b, bf[1][kb].b, a1);
    }
    float bbv[4];
    *(float4*)bbv = *(const float4*)&b1[ncb * 16 + lg * 4];
#pragma unroll
    for (int r = 0; r < 4; ++r) {
      const int c = ncb * 16 + lg * 4 + r;
      float h0 = fmaxf(a0[r] + bbv[r], 0.f);
      float h1 = fmaxf(a1[r] + bbv[r], 0.f);
      float w20[4], w21[4];
      *(float4*)w20 = *(const float4*)&w2s[c * 12];
      *(float4*)w21 = *(const float4*)&w2s[c * 12 + 4];
#pragma unroll
      for (int f = 0; f < 4; ++f) {
        pf0[f]     = fmaf(h0, w20[f], pf0[f]);
        pf0[f + 4] = fmaf(h0, w21[f], pf0[f + 4]);
        pf1[f]     = fmaf(h1, w20[f], pf1[f]);
        pf1[f + 4] = fmaf(h1, w21[f], pf1[f + 4]);
      }
    }
  }
#pragma unroll
  for (int f = 0; f < 8; ++f) {
    pf0[f] += __shfl_xor(pf0[f], 16); pf0[f] += __shfl_xor(pf0[f], 32);
    pf1[f] += __shfl_xor(pf1[f], 16); pf1[f] += __shfl_xor(pf1[f], 32);
  }
  if (lg == 0) {
    ushort s0[8], s1[8];
#pragma unroll
    for (int f = 0; f < 8; ++f) {
      float bb = b2[f];
      s0[f] = f2bs(pf0[f] + bb);
      s1[f] = f2bs(pf1[f] + bb);
    }
    *(uint4*)&fv16[(size_t)(n0 + lr) * 8]      = *(uint4*)s0;
    *(uint4*)&fv16[(size_t)(n0 + 16 + lr) * 8] = *(uint4*)s1;
  }
}

// ------- Kernel 2 (MFMA, hoisted gathers, barrier-free flush-on-change segsum) -------
__global__ __launch_bounds__(256) void k_pairs(
    const ushort* __restrict__ fv16, const int* __restrict__ edge_index,
    const int* __restrict__ didx, const int* __restrict__ batch,
    const ushort* __restrict__ pW0p, const float* __restrict__ b0,
    ushort* __restrict__ y, float* __restrict__ sums1) {
  const int t = threadIdx.x, wv = t >> 6, l = t & 63;
  const int lr = l & 15, lg = l >> 4, c0 = lg * 4;
  const int nbase = blockIdx.x * 512;

  union U { uint4 u; bf16x8 b; };
  U af[4];
#pragma unroll
  for (int ncb = 0; ncb < 4; ++ncb)
    af[ncb].u = *(const uint4*)&pW0p[(ncb * 64 + l) * 8];

  // hoist didx for all tiles (lg<2 lanes)
  int de[4][2];
#pragma unroll
  for (int tile = 0; tile < 4; ++tile)
#pragma unroll
    for (int mt = 0; mt < 2; ++mt) {
      const int n = nbase + tile * 128 + wv * 32 + mt * 16 + lr;
      de[tile][mt] = (lg < 2 && n < NNODES) ? didx[n] : 0;
    }
  // hoist edges for all tiles
  int uu[4][2], vvx[4][2];
#pragma unroll
  for (int tile = 0; tile < 4; ++tile)
#pragma unroll
    for (int mt = 0; mt < 2; ++mt) {
      const int n = nbase + tile * 128 + wv * 32 + mt * 16 + lr;
      if (lg < 2 && n < NNODES) {
        uu[tile][mt]  = edge_index[de[tile][mt]];
        vvx[tile][mt] = edge_index[NEDGES + de[tile][mt]];
      } else { uu[tile][mt] = 0; vvx[tile][mt] = 0; }
    }

  float wsum[4][4];
#pragma unroll
  for (int ncb = 0; ncb < 4; ++ncb)
#pragma unroll
    for (int r = 0; r < 4; ++r) wsum[ncb][r] = 0.f;
  int cur_g = -1;

#define FLUSH_P() do { if (cur_g >= 0) {                                  \
    for (int ncb_ = 0; ncb_ < 4; ++ncb_)                                  \
      for (int r_ = 0; r_ < 4; ++r_) {                                    \
        float w_ = wsum[ncb_][r_];                                        \
        w_ += __shfl_xor(w_, 1); w_ += __shfl_xor(w_, 2);                 \
        w_ += __shfl_xor(w_, 4); w_ += __shfl_xor(w_, 8);                 \
        if (lr == 0) atomicAdd(&sums1[cur_g * 64 + ncb_ * 16 + c0 + r_], w_); \
        wsum[ncb_][r_] = 0.f;                                             \
      } } } while (0)

  for (int tile = 0; tile < 4; ++tile) {
    const int n0 = nbase + tile * 128 + wv * 32;
    if (n0 >= NNODES) break;

    U bf[2];
    int gN[2];
#pragma unroll
    for (int mt = 0; mt < 2; ++mt) {
      const int n = n0 + mt * 16 + lr;
      gN[mt] = batch[n];
      bf[mt].u = make_uint4(0u, 0u, 0u, 0u);
      if (lg < 2) {
        ushort4 bb = *(const ushort4*)&fv16[(size_t)n * 8 + lg * 4];
        ushort4 ub = *(const ushort4*)&fv16[(size_t)uu[tile][mt] * 8 + lg * 4];
        ushort4 vb = *(const ushort4*)&fv16[(size_t)vvx[tile][mt] * 8 + lg * 4];
        const ushort* bp = (const ushort*)&bb;
        const ushort* up = (const ushort*)&ub;
        const ushort* vp = (const ushort*)&vb;
        ushort s[8];
#pragma unroll
        for (int j = 0; j < 4; ++j) {
          s[2 * j] = bp[j];
          float uf = __uint_as_float((unsigned)up[j] << 16);
          float vf = __uint_as_float((unsigned)vp[j] << 16);
          s[2 * j + 1] = (uf > vf) ? up[j] : vp[j];
        }
        bf[mt].u = *(uint4*)s;
      }
    }

    f32x4 acc[2][4];
#pragma unroll
    for (int mt = 0; mt < 2; ++mt)
#pragma unroll
      for (int ncb = 0; ncb < 4; ++ncb) {
        acc[mt][ncb] = (f32x4){0.f, 0.f, 0.f, 0.f};
        acc[mt][ncb] = MFMA16(af[ncb].b, bf[mt].b, acc[mt][ncb]);
      }

    const int g_first = __shfl(gN[0], 0);
    const bool uni = __all(gN[0] == g_first) && __all(gN[1] == g_first);
    if (uni && g_first != cur_g) { FLUSH_P(); cur_g = g_first; }

#pragma unroll
    for (int mt = 0; mt < 2; ++mt) {
      const int n = n0 + mt * 16 + lr;
      const int g = gN[mt];
#pragma unroll
      for (int ncb = 0; ncb < 4; ++ncb) {
        const int c = ncb * 16 + c0;
        float bbv[4];
        *(float4*)bbv = *(const float4*)&b0[c];
        ushort st[4];
#pragma unroll
        for (int r = 0; r < 4; ++r) {
          float v = fmaxf(acc[mt][ncb][r] + bbv[r], 0.f);
          st[r] = f2bs(v);
          if (uni) wsum[ncb][r] += v;
          else atomicAdd(&sums1[g * 64 + c + r], v);  // boundary tiles only
        }
        *(ushort4*)&y[(size_t)n * 64 + c] = *(ushort4*)st;
      }
    }
  }
  FLUSH_P();
#undef FLUSH_P
}

// ---------- xm = (sums/max(cnt,1)) @ LW  (D = 64 or 128) ----------
template <int D>
__global__ void k_meanlin(const float* __restrict__ sums,
                          const int* __restrict__ cnt,
                          const float* __restrict__ LW,
                          float* __restrict__ xm) {
  __shared__ float m[64];
  const int g = blockIdx.x, t = threadIdx.x;
  const float c = fmaxf((float)cnt[g], 1.f);
  if (t < 64) m[t] = sums[g * 64 + t] / c;
  __syncthreads();
  float a = 0.f;
#pragma unroll
  for (int k = 0; k < 64; ++k) a = fmaf(m[k], LW[k * D + t], a);
  xm[g * D + t] = a;
}

// ---- Kernel 4 (MFMA, 2-deep pipeline, barrier-free flush-on-change segsum) ----
__global__ __launch_bounds__(256) void k_ds1(
    const ushort* __restrict__ ybf, const int* __restrict__ batch,
    const ushort* __restrict__ pW1, const float* __restrict__ g1b,
    const float* __restrict__ xm1, ushort* __restrict__ y2,
    float* __restrict__ sums2) {
  const int t = threadIdx.x, wv = t >> 6, l = t & 63;
  const int lr = l & 15, lg = l >> 4, c0 = lg * 4;
  const int nbase = blockIdx.x * 512;

  union U { uint4 u; bf16x8 b; };
  U af[4][2];
#pragma unroll
  for (int ncb = 0; ncb < 4; ++ncb)
#pragma unroll
    for (int kb = 0; kb < 2; ++kb)
      af[ncb][kb].u = *(const uint4*)&pW1[((ncb * 2 + kb) * 64 + l) * 8];

  float wsum[4][4];
#pragma unroll
  for (int ncb = 0; ncb < 4; ++ncb)
#pragma unroll
    for (int r = 0; r < 4; ++r) wsum[ncb][r] = 0.f;
  int cur_g = -1;

#define FLUSH_D() do { if (cur_g >= 0) {                                  \
    for (int ncb_ = 0; ncb_ < 4; ++ncb_)                                  \
      for (int r_ = 0; r_ < 4; ++r_) {                                    \
        float w_ = wsum[ncb_][r_];                                        \
        w_ += __shfl_xor(w_, 1); w_ += __shfl_xor(w_, 2);                 \
        w_ += __shfl_xor(w_, 4); w_ += __shfl_xor(w_, 8);                 \
        if (lr == 0) atomicAdd(&sums2[cur_g * 64 + ncb_ * 16 + c0 + r_], w_); \
        wsum[ncb_][r_] = 0.f;                                             \
      } } } while (0)

  // 2-deep pipeline buffers
  U bfP[2][2], bfQ[2][2];
  {
    const int n0 = nbase + wv * 32;
    if (n0 < NNODES)
#pragma unroll
      for (int mt = 0; mt < 2; ++mt)
#pragma unroll
        for (int kb = 0; kb < 2; ++kb)
          bfP[mt][kb].u = *(const uint4*)&ybf[(size_t)(n0 + mt * 16 + lr) * 64 + kb * 32 + lg * 8];
  }

  for (int tile = 0; tile < 4; ++tile) {
    const int n0 = nbase + tile * 128 + wv * 32;
    if (n0 >= NNODES) break;
    U (*cur)[2] = (tile & 1) ? bfQ : bfP;
    U (*nxt)[2] = (tile & 1) ? bfP : bfQ;
    const int n1 = n0 + 128;
    if (tile < 3 && n1 < NNODES)
#pragma unroll
      for (int mt = 0; mt < 2; ++mt)
#pragma unroll
        for (int kb = 0; kb < 2; ++kb)
          nxt[mt][kb].u = *(const uint4*)&ybf[(size_t)(n1 + mt * 16 + lr) * 64 + kb * 32 + lg * 8];

    f32x4 acc[2][4];
#pragma unroll
    for (int mt = 0; mt < 2; ++mt)
#pragma unroll
      for (int ncb = 0; ncb < 4; ++ncb) {
        acc[mt][ncb] = (f32x4){0.f, 0.f, 0.f, 0.f};
        acc[mt][ncb] = MFMA16(af[ncb][0].b, cur[mt][0].b, acc[mt][ncb]);
        acc[mt][ncb] = MFMA16(af[ncb][1].b, cur[mt][1].b, acc[mt][ncb]);
      }

    const int g0 = batch[n0 + lr], g1 = batch[n0 + 16 + lr];
    const int g_first = __shfl(g0, 0);
    const bool uni = __all(g0 == g_first) && __all(g1 == g_first);
    if (uni && g_first != cur_g) { FLUSH_D(); cur_g = g_first; }

#pragma unroll
    for (int mt = 0; mt < 2; ++mt) {
      const int n = n0 + mt * 16 + lr;
      const int g = mt ? g1 : g0;
#pragma unroll
      for (int ncb = 0; ncb < 4; ++ncb) {
        const int c = ncb * 16 + c0;
        float xmv[4], bbv[4];
        *(float4*)xmv = *(const float4*)&xm1[g * 64 + c];
        *(float4*)bbv = *(const float4*)&g1b[c];
        ushort st[4];
#pragma unroll
        for (int r = 0; r < 4; ++r) {
          float v = fmaxf(acc[mt][ncb][r] + bbv[r] - xmv[r], 0.f);
          st[r] = f2bs(v);
          if (uni) wsum[ncb][r] += v;
          else atomicAdd(&sums2[g * 64 + c + r], v);
        }
        *(ushort4*)&y2[(size_t)n * 64 + c] = *(ushort4*)st;
      }
    }
  }
  FLUSH_D();
#undef FLUSH_D
}

// ---- Kernel 6a (MFMA, 2-deep pipeline, register-accumulated BN stats) ----
__global__ __launch_bounds__(256) void k_ds2a(
    const ushort* __restrict__ y2, const int* __restrict__ batch,
    const ushort* __restrict__ pW2, const float* __restrict__ g2b,
    const float* __restrict__ xm2,
    float* __restrict__ pmu, float* __restrict__ psq) {
  __shared__ float ps[4][128], pq[4][128];
  const int t = threadIdx.x, wv = t >> 6, l = t & 63;
  const int lr = l & 15, lg = l >> 4, c0 = lg * 4;
  const int nbase = blockIdx.x * 512;

  union U { uint4 u; bf16x8 b; };
  float sw[8][4], sq[8][4];
#pragma unroll
  for (int ncb = 0; ncb < 8; ++ncb)
#pragma unroll
    for (int r = 0; r < 4; ++r) { sw[ncb][r] = 0.f; sq[ncb][r] = 0.f; }

  U bfP[2][2], bfQ[2][2];
  {
    const int n0 = nbase + wv * 32;
    if (n0 < NNODES)
#pragma unroll
      for (int mt = 0; mt < 2; ++mt)
#pragma unroll
        for (int kb = 0; kb < 2; ++kb)
          bfP[mt][kb].u = *(const uint4*)&y2[(size_t)(n0 + mt * 16 + lr) * 64 + kb * 32 + lg * 8];
  }

  for (int tile = 0; tile < 4; ++tile) {
    const int n0 = nbase + tile * 128 + wv * 32;
    const bool act = n0 < NNODES;
    U (*cur)[2] = (tile & 1) ? bfQ : bfP;
    U (*nxt)[2] = (tile & 1) ? bfP : bfQ;
    const int n1 = n0 + 128;
    if (tile < 3 && n1 < NNODES)
#pragma unroll
      for (int mt = 0; mt < 2; ++mt)
#pragma unroll
        for (int kb = 0; kb < 2; ++kb)
          nxt[mt][kb].u = *(const uint4*)&y2[(size_t)(n1 + mt * 16 + lr) * 64 + kb * 32 + lg * 8];
    if (!act) continue;

    const int g0 = batch[n0 + lr], g1 = batch[n0 + 16 + lr];

#pragma unroll
    for (int ncb = 0; ncb < 8; ++ncb) {
      U af0, af1;
      af0.u = *(const uint4*)&pW2[((ncb * 2 + 0) * 64 + l) * 8];
      af1.u = *(const uint4*)&pW2[((ncb * 2 + 1) * 64 + l) * 8];
      f32x4 a0 = (f32x4){0.f, 0.f, 0.f, 0.f}, a1 = (f32x4){0.f, 0.f, 0.f, 0.f};
      a0 = MFMA16(af0.b, cur[0][0].b, a0); a0 = MFMA16(af1.b, cur[0][1].b, a0);
      a1 = MFMA16(af0.b, cur[1][0].b, a1); a1 = MFMA16(af1.b, cur[1][1].b, a1);

      const int c = ncb * 16 + c0;
      float xm0[4], xm1v[4], bbv[4];
      *(float4*)xm0 = *(const float4*)&xm2[g0 * 128 + c];
      *(float4*)xm1v = *(const float4*)&xm2[g1 * 128 + c];
      *(float4*)bbv = *(const float4*)&g2b[c];
#pragma unroll
      for (int r = 0; r < 4; ++r) {
        float v0 = fmaxf(a0[r] + bbv[r] - xm0[r], 0.f);
        float v1 = fmaxf(a1[r] + bbv[r] - xm1v[r], 0.f);
        sw[ncb][r] += v0 + v1;
        sq[ncb][r] = fmaf(v0, v0, fmaf(v1, v1, sq[ncb][r]));
      }
    }
  }

#pragma unroll
  for (int ncb = 0; ncb < 8; ++ncb)
#pragma unroll
    for (int r = 0; r < 4; ++r) {
      float wr = sw[ncb][r], qr = sq[ncb][r];
      wr += __shfl_xor(wr, 1); wr += __shfl_xor(wr, 2);
      wr += __shfl_xor(wr, 4); wr += __shfl_xor(wr, 8);
      qr += __shfl_xor(qr, 1); qr += __shfl_xor(qr, 2);
      qr += __shfl_xor(qr, 4); qr += __shfl_xor(qr, 8);
      if (lr == 0) { ps[wv][ncb * 16 + c0 + r] = wr; pq[wv][ncb * 16 + c0 + r] = qr; }
    }
  __syncthreads();
  if (t < 128) {
    pmu[(size_t)blockIdx.x * 128 + t] = ps[0][t] + ps[1][t] + ps[2][t] + ps[3][t];
    psq[(size_t)blockIdx.x * 128 + t] = pq[0][t] + pq[1][t] + pq[2][t] + pq[3][t];
  }
}

// ---- reduce BN partials ----
__global__ void k_red(const float* __restrict__ pmu, const float* __restrict__ psq,
                      float* __restrict__ musum, float* __restrict__ sqsum) {
  const int f = threadIdx.x & 127;
  const bool mu = threadIdx.x < 128;
  const float* src = mu ? pmu : psq;
  float s = 0.f;
  for (int b = blockIdx.x; b < NBLK4; b += 32) s += src[(size_t)b * 128 + f];
  atomicAdd(mu ? &musum[f] : &sqsum[f], s);
}

// ---- Kernel 7 (MFMA fused): recompute h (f32), LDS stage, coalesced BN+residual ----
__global__ __launch_bounds__(256) void k_bn(
    const ushort* __restrict__ y2, const int* __restrict__ batch,
    const ushort* __restrict__ pW2, const float* __restrict__ g2b,
    const float* __restrict__ xm2, const float* __restrict__ x,
    const float* __restrict__ musum, const float* __restrict__ sqsum,
    const float* __restrict__ gamma, const float* __restrict__ beta,
    float* __restrict__ out) {
  __shared__ float vs[64 * 132];
  __shared__ float smu[128], ssc[128], sbe[128];
  const int t = threadIdx.x, wv = t >> 6, l = t & 63;
  const int lr = l & 15, lg = l >> 4, c0 = lg * 4;
  if (t < 128) {
    const float invN = 1.f / (float)NNODES;
    float m = musum[t] * invN;
    float v = sqsum[t] * invN - m * m;
    smu[t] = m;
    ssc[t] = rsqrtf(v + BN_EPS) * gamma[t];
    sbe[t] = beta[t];
  }
  const int nblk = blockIdx.x * 64;
  const int n0 = nblk + wv * 16;

  if (n0 < NNODES) {
    union { uint4 u; bf16x8 b; } bf[2];
#pragma unroll
    for (int kb = 0; kb < 2; ++kb)
      bf[kb].u = *(const uint4*)&y2[(size_t)(n0 + lr) * 64 + kb * 32 + lg * 8];

    const int g0 = batch[n0 + lr];
    const int row0 = wv * 16 + lr;

#pragma unroll
    for (int ncb = 0; ncb < 8; ++ncb) {
      union { uint4 u; bf16x8 b; } af0, af1;
      af0.u = *(const uint4*)&pW2[((ncb * 2 + 0) * 64 + l) * 8];
      af1.u = *(const uint4*)&pW2[((ncb * 2 + 1) * 64 + l) * 8];
      f32x4 a0 = (f32x4){0.f, 0.f, 0.f, 0.f};
      a0 = MFMA16(af0.b, bf[0].b, a0);
      a0 = MFMA16(af1.b, bf[1].b, a0);

      const int c = ncb * 16 + c0;
      float bbv[4], xm0[4], hvv[4];
      *(float4*)bbv = *(const float4*)&g2b[c];
      *(float4*)xm0 = *(const float4*)&xm2[g0 * 128 + c];
#pragma unroll
      for (int r = 0; r < 4; ++r)
        hvv[r] = fmaxf(a0[r] + bbv[r] - xm0[r], 0.f);
      *(float4*)&vs[row0 * 132 + c] = *(float4*)hvv;
    }
  }
  __syncthreads();

  const int rmax = NNODES - nblk;
  for (int i = t; i < 2048; i += 256) {
    const int row = i >> 5, c4 = (i & 31) * 4;
    if (row >= rmax) break;
    const int n = nblk + row;
    float hv[4], muv[4], scv[4], bev[4], xv[4], o[4];
    *(float4*)hv = *(const float4*)&vs[row * 132 + c4];
    *(float4*)muv = *(const float4*)&smu[c4];
    *(float4*)scv = *(const float4*)&ssc[c4];
    *(float4*)bev = *(const float4*)&sbe[c4];
    *(float4*)xv = *(const float4*)&x[(size_t)n * 128 + c4];
#pragma unroll
    for (int r = 0; r < 4; ++r)
      o[r] = xv[r] + (hv[r] - muv[r]) * scv[r] + bev[r];
    *(float4*)&out[(size_t)n * 128 + c4] = *(float4*)o;
  }
}

extern "C" void kernel_launch(void* const* d_in, const int* in_sizes, int n_in,
                              void* d_out, int out_size, void* d_ws,
                              size_t ws_size, hipStream_t stream) {
  const float* x     = (const float*)d_in[0];
  const float* W1    = (const float*)d_in[1];
  const float* b1    = (const float*)d_in[2];
  const float* W2    = (const float*)d_in[3];
  const float* b2    = (const float*)d_in[4];
  const float* W0    = (const float*)d_in[5];
  const float* b0    = (const float*)d_in[6];
  const float* g1W   = (const float*)d_in[7];
  const float* g1b   = (const float*)d_in[8];
  const float* l1W   = (const float*)d_in[9];
  const float* g2W   = (const float*)d_in[10];
  const float* g2b   = (const float*)d_in[11];
  const float* l2W   = (const float*)d_in[12];
  const float* gamma = (const float*)d_in[13];
  const float* beta  = (const float*)d_in[14];
  const int* edge_index = (const int*)d_in[15];
  const int* batch      = (const int*)d_in[16];
  const int* didx       = (const int*)d_in[17];
  float* out = (float*)d_out;

  char* ws = (char*)d_ws;
  ushort* fv16  = (ushort*)(ws + 0);           // 8,000,000 B (dead after k_pairs)
  float*  pmu   = (float*) (ws + 0);           // 500,224 B (reuses fv16)
  float*  psq   = (float*) (ws + 2000384);
  ushort* ybf   = (ushort*)(ws + 16000000);    // 64,000,000 B
  ushort* y2    = (ushort*)(ws + 80000000);    // 64,000,000 B
  float*  sums1 = (float*) (ws + 144000000);
  float*  sums2 = (float*) (ws + 144131072);
  float*  musum = (float*) (ws + 144262144);
  float*  sqsum = (float*) (ws + 144262656);
  int*    cnt   = (int*)   (ws + 144263168);
  float*  xm1   = (float*) (ws + 144265216);
  float*  xm2   = (float*) (ws + 144396288);
  ushort* pW1   = (ushort*)(ws + 144658432);
  ushort* pW2   = (ushort*)(ws + 144666624);
  ushort* pW0   = (ushort*)(ws + 144683008);   // 32,768 B
  ushort* pW0p  = (ushort*)(ws + 144715776);   // 8,192 B

  hipMemsetAsync(ws + 144000000, 0, 263168, stream);

  k_pack<<<64, 256, 0, stream>>>(g1W, g2W, W1, W0, batch, pW1, pW2, pW0, pW0p, cnt);
  k_filt<<<NBLK2, 256, 0, stream>>>(x, pW0, b1, W2, b2, fv16);
  k_pairs<<<NBLK4, 256, 0, stream>>>(fv16, edge_index, didx, batch, pW0p, b0, ybf, sums1);
  k_meanlin<64><<<NGRAPHS, 64, 0, stream>>>(sums1, cnt, l1W, xm1);
  k_ds1<<<NBLK4, 256, 0, stream>>>(ybf, batch, pW1, g1b, xm1, y2, sums2);
  k_meanlin<128><<<NGRAPHS, 128, 0, stream>>>(sums2, cnt, l2W, xm2);
  k_ds2a<<<NBLK4, 256, 0, stream>>>(y2, batch, pW2, g2b, xm2, pmu, psq);
  k_red<<<32, 256, 0, stream>>>(pmu, psq, musum, sqsum);
  k_bn<<<NBLK3, 256, 0, stream>>>(y2, batch, pW2, g2b, xm2, x, musum, sqsum,
                                  gamma, beta, out);
}

// Round 14
// 458.365 us; speedup vs baseline: 1.3605x; 1.3605x over previous
//
#include <hip/hip_runtime.h>
#include <hip/hip_bf16.h>

#define NNODES 500000
#define NEDGES 8000000
#define NGRAPHS 512
#define NFEAT 128
#define NHID 128
#define NFILT 8
#define ODIM 64
#define BN_EPS 1e-5f
#define NBLK2 3907  // ceil(NNODES/128)
#define NBLK3 7813  // ceil(NNODES/64)  for k_bn
#define NBLK4 977   // ceil(NNODES/512) for k_pairs/k_ds1/k_ds2a (4 tiles/block)

typedef __attribute__((ext_vector_type(8))) short bf16x8;
typedef __attribute__((ext_vector_type(4))) float f32x4;
#define MFMA16(a, b, c) __builtin_amdgcn_mfma_f32_16x16x32_bf16(a, b, c, 0, 0, 0)

__device__ inline ushort f2bs(float f) {
  union { __hip_bfloat16 h; ushort u; } cv;
  cv.h = __float2bfloat16(f);
  return cv.u;
}

// ---- pack weights into MFMA A-frag layout + cnt[g] binary search (merged) ----
__global__ void k_pack(const float* __restrict__ g1W, const float* __restrict__ g2W,
                       const float* __restrict__ W1, const float* __restrict__ W0,
                       const int* __restrict__ batch,
                       ushort* __restrict__ pW1, ushort* __restrict__ pW2,
                       ushort* __restrict__ pW0, ushort* __restrict__ pW0p,
                       int* __restrict__ cnt) {
  int idx = blockIdx.x * 256 + threadIdx.x;
  if (idx < 4096) {
    int j = idx & 7, l = (idx >> 3) & 63, kb = (idx >> 9) & 1, ncb = idx >> 10;
    int k = kb * 32 + (l >> 4) * 8 + j, c = ncb * 16 + (l & 15);
    pW1[idx] = f2bs(g1W[k * 64 + c]);
  }
  if (idx < 8192) {
    int j = idx & 7, l = (idx >> 3) & 63, kb = (idx >> 9) & 1, ncb = idx >> 10;
    int k = kb * 32 + (l >> 4) * 8 + j, c = ncb * 16 + (l & 15);
    pW2[idx] = f2bs(g2W[k * 128 + c]);
  }
  if (idx < 16384) {
    int j = idx & 7, l = (idx >> 3) & 63, kb = (idx >> 9) & 3, ncb = idx >> 11;
    int k = kb * 32 + (l >> 4) * 8 + j, c = ncb * 16 + (l & 15);
    pW0[idx] = f2bs(W1[k * 128 + c]);
  }
  if (idx < 4096) {
    int j = idx & 7, l = (idx >> 3) & 63, ncb = idx >> 9;
    int k = (l >> 4) * 8 + j, c = ncb * 16 + (l & 15);
    pW0p[idx] = (k < 16) ? f2bs(W0[k * 64 + c]) : (ushort)0;
  }
  if (idx < NGRAPHS) {
    int g = idx;
    int lo0 = 0, hi0 = NNODES;
    while (lo0 < hi0) { int mid = (lo0 + hi0) >> 1; if (batch[mid] < g) lo0 = mid + 1; else hi0 = mid; }
    int lo1 = lo0, hi1 = NNODES;
    while (lo1 < hi1) { int mid = (lo1 + hi1) >> 1; if (batch[mid] < g + 1) lo1 = mid + 1; else hi1 = mid; }
    cnt[g] = lo1 - lo0;
  }
}

// ---- Kernel 1 (MFMA): fv16 = bf16( relu(x@W1+b1)@W2 + b2 )  [N,8] ----
__global__ __launch_bounds__(256) void k_filt(
    const float* __restrict__ x, const ushort* __restrict__ pW0,
    const float* __restrict__ b1, const float* __restrict__ W2,
    const float* __restrict__ b2, ushort* __restrict__ fv16) {
  __shared__ float w2s[128 * 12];
  const int t = threadIdx.x;
  for (int i = t; i < 1024; i += 256) {
    int c = i >> 3, f = i & 7;
    w2s[c * 12 + f] = W2[i];
  }
  __syncthreads();
  const int wv = t >> 6, l = t & 63;
  const int lr = l & 15, lg = l >> 4;
  const int n0 = blockIdx.x * 128 + wv * 32;
  if (n0 >= NNODES) return;

  union { uint4 u; bf16x8 b; } bf[2][4];
#pragma unroll
  for (int mt = 0; mt < 2; ++mt)
#pragma unroll
    for (int kb = 0; kb < 4; ++kb) {
      const float* src = &x[(size_t)(n0 + mt * 16 + lr) * 128 + kb * 32 + lg * 8];
      float v[8];
      *(float4*)&v[0] = *(const float4*)src;
      *(float4*)&v[4] = *(const float4*)(src + 4);
      ushort s[8];
#pragma unroll
      for (int e = 0; e < 8; ++e) s[e] = f2bs(v[e]);
      bf[mt][kb].u = *(uint4*)s;
    }

  float pf0[8], pf1[8];
#pragma unroll
  for (int f = 0; f < 8; ++f) { pf0[f] = 0.f; pf1[f] = 0.f; }

#pragma unroll
  for (int ncb = 0; ncb < 8; ++ncb) {
    union { uint4 u; bf16x8 b; } af[4];
#pragma unroll
    for (int kb = 0; kb < 4; ++kb)
      af[kb].u = *(const uint4*)&pW0[((ncb * 4 + kb) * 64 + l) * 8];
    f32x4 a0 = (f32x4){0.f, 0.f, 0.f, 0.f};
    f32x4 a1 = (f32x4){0.f, 0.f, 0.f, 0.f};
#pragma unroll
    for (int kb = 0; kb < 4; ++kb) {
      a0 = MFMA16(af[kb].b, bf[0][kb].b, a0);
      a1 = MFMA16(af[kb].b, bf[1][kb].b, a1);
    }
    float bbv[4];
    *(float4*)bbv = *(const float4*)&b1[ncb * 16 + lg * 4];
#pragma unroll
    for (int r = 0; r < 4; ++r) {
      const int c = ncb * 16 + lg * 4 + r;
      float h0 = fmaxf(a0[r] + bbv[r], 0.f);
      float h1 = fmaxf(a1[r] + bbv[r], 0.f);
      float w20[4], w21[4];
      *(float4*)w20 = *(const float4*)&w2s[c * 12];
      *(float4*)w21 = *(const float4*)&w2s[c * 12 + 4];
#pragma unroll
      for (int f = 0; f < 4; ++f) {
        pf0[f]     = fmaf(h0, w20[f], pf0[f]);
        pf0[f + 4] = fmaf(h0, w21[f], pf0[f + 4]);
        pf1[f]     = fmaf(h1, w20[f], pf1[f]);
        pf1[f + 4] = fmaf(h1, w21[f], pf1[f + 4]);
      }
    }
  }
#pragma unroll
  for (int f = 0; f < 8; ++f) {
    pf0[f] += __shfl_xor(pf0[f], 16); pf0[f] += __shfl_xor(pf0[f], 32);
    pf1[f] += __shfl_xor(pf1[f], 16); pf1[f] += __shfl_xor(pf1[f], 32);
  }
  if (lg == 0) {
    ushort s0[8], s1[8];
#pragma unroll
    for (int f = 0; f < 8; ++f) {
      float bb = b2[f];
      s0[f] = f2bs(pf0[f] + bb);
      s1[f] = f2bs(pf1[f] + bb);
    }
    *(uint4*)&fv16[(size_t)(n0 + lr) * 8]      = *(uint4*)s0;
    *(uint4*)&fv16[(size_t)(n0 + 16 + lr) * 8] = *(uint4*)s1;
  }
}

// ------- Kernel 2 (MFMA, lane-parallel gathers): pairs + y = relu(x16@W0+b0) bf16;
//         block-reduced segsum1; boundary rows via tile-local 2nd accumulator. -------
__global__ __launch_bounds__(256) void k_pairs(
    const ushort* __restrict__ fv16, const int* __restrict__ edge_index,
    const int* __restrict__ didx, const int* __restrict__ batch,
    const ushort* __restrict__ pW0p, const float* __restrict__ b0,
    ushort* __restrict__ y, float* __restrict__ sums1) {
  __shared__ float ps[4][64];
  __shared__ int pg[4];
  const int t = threadIdx.x, wv = t >> 6, l = t & 63;
  const int lr = l & 15, lg = l >> 4, c0 = lg * 4;
  const int nbase = blockIdx.x * 512;

  union U { uint4 u; bf16x8 b; };
  U af[4];
#pragma unroll
  for (int ncb = 0; ncb < 4; ++ncb)
    af[ncb].u = *(const uint4*)&pW0p[(ncb * 64 + l) * 8];

  for (int tile = 0; tile < 4; ++tile) {
    const int n0 = nbase + tile * 128 + wv * 32;
    if (n0 < NNODES) {
      U bf[2];
      int gN[2];
#pragma unroll
      for (int mt = 0; mt < 2; ++mt) {
        const int n = n0 + mt * 16 + lr;
        gN[mt] = batch[n];
        bf[mt].u = make_uint4(0u, 0u, 0u, 0u);
        if (lg < 2) {
          const int de = didx[n];
          const int u = edge_index[de];
          const int v = edge_index[NEDGES + de];
          ushort4 bb = *(const ushort4*)&fv16[(size_t)n * 8 + lg * 4];
          ushort4 ub = *(const ushort4*)&fv16[(size_t)u * 8 + lg * 4];
          ushort4 vb = *(const ushort4*)&fv16[(size_t)v * 8 + lg * 4];
          const ushort* bp = (const ushort*)&bb;
          const ushort* up = (const ushort*)&ub;
          const ushort* vp = (const ushort*)&vb;
          ushort s[8];
#pragma unroll
          for (int j = 0; j < 4; ++j) {
            s[2 * j] = bp[j];
            float uf = __uint_as_float((unsigned)up[j] << 16);
            float vf = __uint_as_float((unsigned)vp[j] << 16);
            s[2 * j + 1] = (uf > vf) ? up[j] : vp[j];
          }
          bf[mt].u = *(uint4*)s;
        }
      }

      f32x4 acc[2][4];
#pragma unroll
      for (int mt = 0; mt < 2; ++mt)
#pragma unroll
        for (int ncb = 0; ncb < 4; ++ncb) {
          acc[mt][ncb] = (f32x4){0.f, 0.f, 0.f, 0.f};
          acc[mt][ncb] = MFMA16(af[ncb].b, bf[mt].b, acc[mt][ncb]);
        }

      const int g_first = __shfl(gN[0], 0);
      const int g_last  = __shfl(gN[1], 15);  // max graph in wave (sorted batch)
      const bool bnd = (g_last != g_first);
      float wsum[4][4], np[4][4];
#pragma unroll
      for (int ncb = 0; ncb < 4; ++ncb)
#pragma unroll
        for (int r = 0; r < 4; ++r) { wsum[ncb][r] = 0.f; np[ncb][r] = 0.f; }

#pragma unroll
      for (int mt = 0; mt < 2; ++mt) {
        const int n = n0 + mt * 16 + lr;
        const int g = gN[mt];
#pragma unroll
        for (int ncb = 0; ncb < 4; ++ncb) {
          const int c = ncb * 16 + c0;
          float bbv[4];
          *(float4*)bbv = *(const float4*)&b0[c];
          ushort st[4];
#pragma unroll
          for (int r = 0; r < 4; ++r) {
            float v = fmaxf(acc[mt][ncb][r] + bbv[r], 0.f);
            st[r] = f2bs(v);
            if (g == g_first) wsum[ncb][r] += v;
            else if (g == g_last) np[ncb][r] += v;
            else atomicAdd(&sums1[g * 64 + c + r], v);  // ~never (3-graph wave)
          }
          *(ushort4*)&y[(size_t)n * 64 + c] = *(ushort4*)st;
        }
      }
#pragma unroll
      for (int ncb = 0; ncb < 4; ++ncb)
#pragma unroll
        for (int r = 0; r < 4; ++r) {
          float w = wsum[ncb][r];
          w += __shfl_xor(w, 1); w += __shfl_xor(w, 2);
          w += __shfl_xor(w, 4); w += __shfl_xor(w, 8);
          if (lr == 0) ps[wv][ncb * 16 + c0 + r] = w;
        }
      if (l == 0) pg[wv] = g_first;
      if (bnd) {
#pragma unroll
        for (int ncb = 0; ncb < 4; ++ncb)
#pragma unroll
          for (int r = 0; r < 4; ++r) {
            float w = np[ncb][r];
            w += __shfl_xor(w, 1); w += __shfl_xor(w, 2);
            w += __shfl_xor(w, 4); w += __shfl_xor(w, 8);
            if (lr == 0) atomicAdd(&sums1[g_last * 64 + ncb * 16 + c0 + r], w);
          }
      }
    } else {
      ps[wv][l] = 0.f;
      if (l == 0) pg[wv] = -1;
    }
    __syncthreads();

    if (t < 64) {
      const int bg = pg[0];
      float s = 0.f;
#pragma unroll
      for (int w = 0; w < 4; ++w) {
        const int gv = pg[w];
        if (gv < 0) continue;
        if (gv == bg) s += ps[w][t];
        else atomicAdd(&sums1[gv * 64 + t], ps[w][t]);
      }
      if (bg >= 0) atomicAdd(&sums1[bg * 64 + t], s);
    }
    __syncthreads();
  }
}

// ---------- xm = (sums/max(cnt,1)) @ LW  (D = 64 or 128) ----------
template <int D>
__global__ void k_meanlin(const float* __restrict__ sums,
                          const int* __restrict__ cnt,
                          const float* __restrict__ LW,
                          float* __restrict__ xm) {
  __shared__ float m[64];
  const int g = blockIdx.x, t = threadIdx.x;
  const float c = fmaxf((float)cnt[g], 1.f);
  if (t < 64) m[t] = sums[g * 64 + t] / c;
  __syncthreads();
  float a = 0.f;
#pragma unroll
  for (int k = 0; k < 64; ++k) a = fmaf(m[k], LW[k * D + t], a);
  xm[g * D + t] = a;
}

// ---- Kernel 4 (MFMA, 4 tiles/block): y2 = relu(y@g1W+g1b-xm1[g]) bf16;
//      block-reduced segsum2; boundary rows via tile-local 2nd accumulator ----
__global__ __launch_bounds__(256) void k_ds1(
    const ushort* __restrict__ ybf, const int* __restrict__ batch,
    const ushort* __restrict__ pW1, const float* __restrict__ g1b,
    const float* __restrict__ xm1, ushort* __restrict__ y2,
    float* __restrict__ sums2) {
  __shared__ float ps[4][64];
  __shared__ int pg[4];
  const int t = threadIdx.x, wv = t >> 6, l = t & 63;
  const int lr = l & 15, lg = l >> 4, c0 = lg * 4;
  const int nbase = blockIdx.x * 512;

  union U { uint4 u; bf16x8 b; };
  U af[4][2];
#pragma unroll
  for (int ncb = 0; ncb < 4; ++ncb)
#pragma unroll
    for (int kb = 0; kb < 2; ++kb)
      af[ncb][kb].u = *(const uint4*)&pW1[((ncb * 2 + kb) * 64 + l) * 8];

  for (int tile = 0; tile < 4; ++tile) {
    const int n0 = nbase + tile * 128 + wv * 32;
    if (n0 < NNODES) {
      U bf[2][2];
#pragma unroll
      for (int mt = 0; mt < 2; ++mt)
#pragma unroll
        for (int kb = 0; kb < 2; ++kb)
          bf[mt][kb].u = *(const uint4*)&ybf[(size_t)(n0 + mt * 16 + lr) * 64 + kb * 32 + lg * 8];

      f32x4 acc[2][4];
#pragma unroll
      for (int mt = 0; mt < 2; ++mt)
#pragma unroll
        for (int ncb = 0; ncb < 4; ++ncb) {
          acc[mt][ncb] = (f32x4){0.f, 0.f, 0.f, 0.f};
          acc[mt][ncb] = MFMA16(af[ncb][0].b, bf[mt][0].b, acc[mt][ncb]);
          acc[mt][ncb] = MFMA16(af[ncb][1].b, bf[mt][1].b, acc[mt][ncb]);
        }

      const int g0 = batch[n0 + lr], g1 = batch[n0 + 16 + lr];
      const int g_first = __shfl(g0, 0);
      const int g_last  = __shfl(g1, 15);
      const bool bnd = (g_last != g_first);

      float wsum[4][4], np[4][4];
#pragma unroll
      for (int ncb = 0; ncb < 4; ++ncb)
#pragma unroll
        for (int r = 0; r < 4; ++r) { wsum[ncb][r] = 0.f; np[ncb][r] = 0.f; }

#pragma unroll
      for (int mt = 0; mt < 2; ++mt) {
        const int n = n0 + mt * 16 + lr;
        const int g = mt ? g1 : g0;
#pragma unroll
        for (int ncb = 0; ncb < 4; ++ncb) {
          const int c = ncb * 16 + c0;
          float xmv[4], bbv[4];
          *(float4*)xmv = *(const float4*)&xm1[g * 64 + c];
          *(float4*)bbv = *(const float4*)&g1b[c];
          ushort st[4];
#pragma unroll
          for (int r = 0; r < 4; ++r) {
            float v = fmaxf(acc[mt][ncb][r] + bbv[r] - xmv[r], 0.f);
            st[r] = f2bs(v);
            if (g == g_first) wsum[ncb][r] += v;
            else if (g == g_last) np[ncb][r] += v;
            else atomicAdd(&sums2[g * 64 + c + r], v);  // ~never
          }
          *(ushort4*)&y2[(size_t)n * 64 + c] = *(ushort4*)st;
        }
      }
#pragma unroll
      for (int ncb = 0; ncb < 4; ++ncb)
#pragma unroll
        for (int r = 0; r < 4; ++r) {
          float w = wsum[ncb][r];
          w += __shfl_xor(w, 1); w += __shfl_xor(w, 2);
          w += __shfl_xor(w, 4); w += __shfl_xor(w, 8);
          if (lr == 0) ps[wv][ncb * 16 + c0 + r] = w;
        }
      if (l == 0) pg[wv] = g_first;
      if (bnd) {
#pragma unroll
        for (int ncb = 0; ncb < 4; ++ncb)
#pragma unroll
          for (int r = 0; r < 4; ++r) {
            float w = np[ncb][r];
            w += __shfl_xor(w, 1); w += __shfl_xor(w, 2);
            w += __shfl_xor(w, 4); w += __shfl_xor(w, 8);
            if (lr == 0) atomicAdd(&sums2[g_last * 64 + ncb * 16 + c0 + r], w);
          }
      }
    } else {
      ps[wv][l] = 0.f;
      if (l == 0) pg[wv] = -1;
    }
    __syncthreads();

    if (t < 64) {
      const int bg = pg[0];
      float s = 0.f;
#pragma unroll
      for (int w = 0; w < 4; ++w) {
        const int gv = pg[w];
        if (gv < 0) continue;
        if (gv == bg) s += ps[w][t];
        else atomicAdd(&sums2[gv * 64 + t], ps[w][t]);
      }
      if (bg >= 0) atomicAdd(&sums2[bg * 64 + t], s);
    }
    __syncthreads();
  }
}

// ---- Kernel 6a (MFMA, 4 tiles/block, register-accumulated BN stats) ----
__global__ __launch_bounds__(256) void k_ds2a(
    const ushort* __restrict__ y2, const int* __restrict__ batch,
    const ushort* __restrict__ pW2, const float* __restrict__ g2b,
    const float* __restrict__ xm2,
    float* __restrict__ pmu, float* __restrict__ psq) {
  __shared__ float ps[4][128], pq[4][128];
  const int t = threadIdx.x, wv = t >> 6, l = t & 63;
  const int lr = l & 15, lg = l >> 4, c0 = lg * 4;
  const int nbase = blockIdx.x * 512;

  float sw[8][4], sq[8][4];
#pragma unroll
  for (int ncb = 0; ncb < 8; ++ncb)
#pragma unroll
    for (int r = 0; r < 4; ++r) { sw[ncb][r] = 0.f; sq[ncb][r] = 0.f; }

  for (int tile = 0; tile < 4; ++tile) {
    const int n0 = nbase + tile * 128 + wv * 32;
    if (n0 >= NNODES) continue;

    union { uint4 u; bf16x8 b; } bf[2][2];
#pragma unroll
    for (int mt = 0; mt < 2; ++mt)
#pragma unroll
      for (int kb = 0; kb < 2; ++kb)
        bf[mt][kb].u = *(const uint4*)&y2[(size_t)(n0 + mt * 16 + lr) * 64 + kb * 32 + lg * 8];

    const int g0 = batch[n0 + lr], g1 = batch[n0 + 16 + lr];

#pragma unroll
    for (int ncb = 0; ncb < 8; ++ncb) {
      union { uint4 u; bf16x8 b; } af0, af1;
      af0.u = *(const uint4*)&pW2[((ncb * 2 + 0) * 64 + l) * 8];
      af1.u = *(const uint4*)&pW2[((ncb * 2 + 1) * 64 + l) * 8];
      f32x4 a0 = (f32x4){0.f, 0.f, 0.f, 0.f}, a1 = (f32x4){0.f, 0.f, 0.f, 0.f};
      a0 = MFMA16(af0.b, bf[0][0].b, a0); a0 = MFMA16(af1.b, bf[0][1].b, a0);
      a1 = MFMA16(af0.b, bf[1][0].b, a1); a1 = MFMA16(af1.b, bf[1][1].b, a1);

      const int c = ncb * 16 + c0;
      float xm0[4], xm1v[4], bbv[4];
      *(float4*)xm0 = *(const float4*)&xm2[g0 * 128 + c];
      *(float4*)xm1v = *(const float4*)&xm2[g1 * 128 + c];
      *(float4*)bbv = *(const float4*)&g2b[c];
#pragma unroll
      for (int r = 0; r < 4; ++r) {
        float v0 = fmaxf(a0[r] + bbv[r] - xm0[r], 0.f);
        float v1 = fmaxf(a1[r] + bbv[r] - xm1v[r], 0.f);
        sw[ncb][r] += v0 + v1;
        sq[ncb][r] = fmaf(v0, v0, fmaf(v1, v1, sq[ncb][r]));
      }
    }
  }

#pragma unroll
  for (int ncb = 0; ncb < 8; ++ncb)
#pragma unroll
    for (int r = 0; r < 4; ++r) {
      float wr = sw[ncb][r], qr = sq[ncb][r];
      wr += __shfl_xor(wr, 1); wr += __shfl_xor(wr, 2);
      wr += __shfl_xor(wr, 4); wr += __shfl_xor(wr, 8);
      qr += __shfl_xor(qr, 1); qr += __shfl_xor(qr, 2);
      qr += __shfl_xor(qr, 4); qr += __shfl_xor(qr, 8);
      if (lr == 0) { ps[wv][ncb * 16 + c0 + r] = wr; pq[wv][ncb * 16 + c0 + r] = qr; }
    }
  __syncthreads();
  if (t < 128) {
    pmu[(size_t)blockIdx.x * 128 + t] = ps[0][t] + ps[1][t] + ps[2][t] + ps[3][t];
    psq[(size_t)blockIdx.x * 128 + t] = pq[0][t] + pq[1][t] + pq[2][t] + pq[3][t];
  }
}

// ---- reduce BN partials ----
__global__ void k_red(const float* __restrict__ pmu, const float* __restrict__ psq,
                      float* __restrict__ musum, float* __restrict__ sqsum) {
  const int f = threadIdx.x & 127;
  const bool mu = threadIdx.x < 128;
  const float* src = mu ? pmu : psq;
  float s = 0.f;
  for (int b = blockIdx.x; b < NBLK4; b += 32) s += src[(size_t)b * 128 + f];
  atomicAdd(mu ? &musum[f] : &sqsum[f], s);
}

// ---- Kernel 7 (MFMA fused): recompute h (f32), LDS stage, coalesced BN+residual ----
__global__ __launch_bounds__(256) void k_bn(
    const ushort* __restrict__ y2, const int* __restrict__ batch,
    const ushort* __restrict__ pW2, const float* __restrict__ g2b,
    const float* __restrict__ xm2, const float* __restrict__ x,
    const float* __restrict__ musum, const float* __restrict__ sqsum,
    const float* __restrict__ gamma, const float* __restrict__ beta,
    float* __restrict__ out) {
  __shared__ float vs[64 * 132];
  __shared__ float smu[128], ssc[128], sbe[128];
  const int t = threadIdx.x, wv = t >> 6, l = t & 63;
  const int lr = l & 15, lg = l >> 4, c0 = lg * 4;
  if (t < 128) {
    const float invN = 1.f / (float)NNODES;
    float m = musum[t] * invN;
    float v = sqsum[t] * invN - m * m;
    smu[t] = m;
    ssc[t] = rsqrtf(v + BN_EPS) * gamma[t];
    sbe[t] = beta[t];
  }
  const int nblk = blockIdx.x * 64;
  const int n0 = nblk + wv * 16;

  if (n0 < NNODES) {
    union { uint4 u; bf16x8 b; } bf[2];
#pragma unroll
    for (int kb = 0; kb < 2; ++kb)
      bf[kb].u = *(const uint4*)&y2[(size_t)(n0 + lr) * 64 + kb * 32 + lg * 8];

    const int g0 = batch[n0 + lr];
    const int row0 = wv * 16 + lr;

#pragma unroll
    for (int ncb = 0; ncb < 8; ++ncb) {
      union { uint4 u; bf16x8 b; } af0, af1;
      af0.u = *(const uint4*)&pW2[((ncb * 2 + 0) * 64 + l) * 8];
      af1.u = *(const uint4*)&pW2[((ncb * 2 + 1) * 64 + l) * 8];
      f32x4 a0 = (f32x4){0.f, 0.f, 0.f, 0.f};
      a0 = MFMA16(af0.b, bf[0].b, a0);
      a0 = MFMA16(af1.b, bf[1].b, a0);

      const int c = ncb * 16 + c0;
      float bbv[4], xm0[4], hvv[4];
      *(float4*)bbv = *(const float4*)&g2b[c];
      *(float4*)xm0 = *(const float4*)&xm2[g0 * 128 + c];
#pragma unroll
      for (int r = 0; r < 4; ++r)
        hvv[r] = fmaxf(a0[r] + bbv[r] - xm0[r], 0.f);
      *(float4*)&vs[row0 * 132 + c] = *(float4*)hvv;
    }
  }
  __syncthreads();

  const int rmax = NNODES - nblk;
  for (int i = t; i < 2048; i += 256) {
    const int row = i >> 5, c4 = (i & 31) * 4;
    if (row >= rmax) break;
    const int n = nblk + row;
    float hv[4], muv[4], scv[4], bev[4], xv[4], o[4];
    *(float4*)hv = *(const float4*)&vs[row * 132 + c4];
    *(float4*)muv = *(const float4*)&smu[c4];
    *(float4*)scv = *(const float4*)&ssc[c4];
    *(float4*)bev = *(const float4*)&sbe[c4];
    *(float4*)xv = *(const float4*)&x[(size_t)n * 128 + c4];
#pragma unroll
    for (int r = 0; r < 4; ++r)
      o[r] = xv[r] + (hv[r] - muv[r]) * scv[r] + bev[r];
    *(float4*)&out[(size_t)n * 128 + c4] = *(float4*)o;
  }
}

extern "C" void kernel_launch(void* const* d_in, const int* in_sizes, int n_in,
                              void* d_out, int out_size, void* d_ws,
                              size_t ws_size, hipStream_t stream) {
  const float* x     = (const float*)d_in[0];
  const float* W1    = (const float*)d_in[1];
  const float* b1    = (const float*)d_in[2];
  const float* W2    = (const float*)d_in[3];
  const float* b2    = (const float*)d_in[4];
  const float* W0    = (const float*)d_in[5];
  const float* b0    = (const float*)d_in[6];
  const float* g1W   = (const float*)d_in[7];
  const float* g1b   = (const float*)d_in[8];
  const float* l1W   = (const float*)d_in[9];
  const float* g2W   = (const float*)d_in[10];
  const float* g2b   = (const float*)d_in[11];
  const float* l2W   = (const float*)d_in[12];
  const float* gamma = (const float*)d_in[13];
  const float* beta  = (const float*)d_in[14];
  const int* edge_index = (const int*)d_in[15];
  const int* batch      = (const int*)d_in[16];
  const int* didx       = (const int*)d_in[17];
  float* out = (float*)d_out;

  char* ws = (char*)d_ws;
  ushort* fv16  = (ushort*)(ws + 0);           // 8,000,000 B (dead after k_pairs)
  float*  pmu   = (float*) (ws + 0);           // 500,224 B (reuses fv16)
  float*  psq   = (float*) (ws + 2000384);
  ushort* ybf   = (ushort*)(ws + 16000000);    // 64,000,000 B
  ushort* y2    = (ushort*)(ws + 80000000);    // 64,000,000 B
  float*  sums1 = (float*) (ws + 144000000);
  float*  sums2 = (float*) (ws + 144131072);
  float*  musum = (float*) (ws + 144262144);
  float*  sqsum = (float*) (ws + 144262656);
  int*    cnt   = (int*)   (ws + 144263168);
  float*  xm1   = (float*) (ws + 144265216);
  float*  xm2   = (float*) (ws + 144396288);
  ushort* pW1   = (ushort*)(ws + 144658432);
  ushort* pW2   = (ushort*)(ws + 144666624);
  ushort* pW0   = (ushort*)(ws + 144683008);   // 32,768 B
  ushort* pW0p  = (ushort*)(ws + 144715776);   // 8,192 B

  hipMemsetAsync(ws + 144000000, 0, 263168, stream);

  k_pack<<<64, 256, 0, stream>>>(g1W, g2W, W1, W0, batch, pW1, pW2, pW0, pW0p, cnt);
  k_filt<<<NBLK2, 256, 0, stream>>>(x, pW0, b1, W2, b2, fv16);
  k_pairs<<<NBLK4, 256, 0, stream>>>(fv16, edge_index, didx, batch, pW0p, b0, ybf, sums1);
  k_meanlin<64><<<NGRAPHS, 64, 0, stream>>>(sums1, cnt, l1W, xm1);
  k_ds1<<<NBLK4, 256, 0, stream>>>(ybf, batch, pW1, g1b, xm1, y2, sums2);
  k_meanlin<128><<<NGRAPHS, 128, 0, stream>>>(sums2, cnt, l2W, xm2);
  k_ds2a<<<NBLK4, 256, 0, stream>>>(y2, batch, pW2, g2b, xm2, pmu, psq);
  k_red<<<32, 256, 0, stream>>>(pmu, psq, musum, sqsum);
  k_bn<<<NBLK3, 256, 0, stream>>>(y2, batch, pW2, g2b, xm2, x, musum, sqsum,
                                  gamma, beta, out);
}

// Round 15
// 457.217 us; speedup vs baseline: 1.3640x; 1.0025x over previous
//
#include <hip/hip_runtime.h>
#include <hip/hip_bf16.h>

#define NNODES 500000
#define NEDGES 8000000
#define NGRAPHS 512
#define NFEAT 128
#define NHID 128
#define NFILT 8
#define ODIM 64
#define BN_EPS 1e-5f
#define NBLK2 3907  // ceil(NNODES/128)
#define NBLK3 7813  // ceil(NNODES/64)  for k_bn
#define NBLK4 977   // ceil(NNODES/512) for k_pairs/k_ds1/k_ds2a (4 tiles/block)

typedef __attribute__((ext_vector_type(8))) short bf16x8;
typedef __attribute__((ext_vector_type(4))) float f32x4;
#define MFMA16(a, b, c) __builtin_amdgcn_mfma_f32_16x16x32_bf16(a, b, c, 0, 0, 0)

__device__ inline ushort f2bs(float f) {
  union { __hip_bfloat16 h; ushort u; } cv;
  cv.h = __float2bfloat16(f);
  return cv.u;
}

// ---- pack weights into MFMA A-frag layout + cnt[g] binary search (merged) ----
__global__ void k_pack(const float* __restrict__ g1W, const float* __restrict__ g2W,
                       const float* __restrict__ W1, const float* __restrict__ W0,
                       const float* __restrict__ W2, const int* __restrict__ batch,
                       ushort* __restrict__ pW1, ushort* __restrict__ pW2,
                       ushort* __restrict__ pW0, ushort* __restrict__ pW0p,
                       ushort* __restrict__ pW2p, int* __restrict__ cnt) {
  int idx = blockIdx.x * 256 + threadIdx.x;
  if (idx < 4096) {
    int j = idx & 7, l = (idx >> 3) & 63, kb = (idx >> 9) & 1, ncb = idx >> 10;
    int k = kb * 32 + (l >> 4) * 8 + j, c = ncb * 16 + (l & 15);
    pW1[idx] = f2bs(g1W[k * 64 + c]);
  }
  if (idx < 8192) {
    int j = idx & 7, l = (idx >> 3) & 63, kb = (idx >> 9) & 1, ncb = idx >> 10;
    int k = kb * 32 + (l >> 4) * 8 + j, c = ncb * 16 + (l & 15);
    pW2[idx] = f2bs(g2W[k * 128 + c]);
  }
  if (idx < 16384) {
    int j = idx & 7, l = (idx >> 3) & 63, kb = (idx >> 9) & 3, ncb = idx >> 11;
    int k = kb * 32 + (l >> 4) * 8 + j, c = ncb * 16 + (l & 15);
    pW0[idx] = f2bs(W1[k * 128 + c]);
  }
  if (idx < 4096) {
    int j = idx & 7, l = (idx >> 3) & 63, ncb = idx >> 9;
    int k = (l >> 4) * 8 + j, c = ncb * 16 + (l & 15);
    pW0p[idx] = (k < 16) ? f2bs(W0[k * 64 + c]) : (ushort)0;
  }
  if (idx < 4096) {  // pW2p: W2 [128x8] -> A[m<16][k<128], zero-pad m>=8
    int j = idx & 7, l = (idx >> 3) & 63, kb = idx >> 9;
    int k = kb * 32 + (l >> 4) * 8 + j, m = l & 15;
    pW2p[idx] = (m < 8) ? f2bs(W2[k * 8 + m]) : (ushort)0;
  }
  if (idx < NGRAPHS) {
    int g = idx;
    int lo0 = 0, hi0 = NNODES;
    while (lo0 < hi0) { int mid = (lo0 + hi0) >> 1; if (batch[mid] < g) lo0 = mid + 1; else hi0 = mid; }
    int lo1 = lo0, hi1 = NNODES;
    while (lo1 < hi1) { int mid = (lo1 + hi1) >> 1; if (batch[mid] < g + 1) lo1 = mid + 1; else hi1 = mid; }
    cnt[g] = lo1 - lo0;
  }
}

// ---- Kernel 1 (all-MFMA): fv16 = bf16( relu(x@W1+b1)@W2 + b2 )  [N,8] ----
// GEMM1 MFMA -> h bf16 to wave-private LDS -> GEMM2 MFMA (W2 zero-padded to 16 cols).
__global__ __launch_bounds__(256) void k_filt(
    const float* __restrict__ x, const ushort* __restrict__ pW0,
    const float* __restrict__ b1, const ushort* __restrict__ pW2p,
    const float* __restrict__ b2, ushort* __restrict__ fv16) {
  __shared__ ushort hs[4 * 32 * 132];  // 33,792 B; wave-private 32x132 tiles
  const int t = threadIdx.x;
  const int wv = t >> 6, l = t & 63;
  const int lr = l & 15, lg = l >> 4;
  const int n0 = blockIdx.x * 128 + wv * 32;
  if (n0 >= NNODES) return;  // no barriers anywhere: wave-private LDS only
  ushort* hw = &hs[wv * 32 * 132];

  // B-frags: x rows f32 -> bf16 in registers
  union { uint4 u; bf16x8 b; } bf[2][4];
#pragma unroll
  for (int mt = 0; mt < 2; ++mt)
#pragma unroll
    for (int kb = 0; kb < 4; ++kb) {
      const float* src = &x[(size_t)(n0 + mt * 16 + lr) * 128 + kb * 32 + lg * 8];
      float v[8];
      *(float4*)&v[0] = *(const float4*)src;
      *(float4*)&v[4] = *(const float4*)(src + 4);
      ushort s[8];
#pragma unroll
      for (int e = 0; e < 8; ++e) s[e] = f2bs(v[e]);
      bf[mt][kb].u = *(uint4*)s;
    }

  // GEMM1: per ncb, 8 MFMA -> relu+bias -> bf16 -> LDS
#pragma unroll
  for (int ncb = 0; ncb < 8; ++ncb) {
    union { uint4 u; bf16x8 b; } af[4];
#pragma unroll
    for (int kb = 0; kb < 4; ++kb)
      af[kb].u = *(const uint4*)&pW0[((ncb * 4 + kb) * 64 + l) * 8];
    f32x4 a0 = (f32x4){0.f, 0.f, 0.f, 0.f};
    f32x4 a1 = (f32x4){0.f, 0.f, 0.f, 0.f};
#pragma unroll
    for (int kb = 0; kb < 4; ++kb) {
      a0 = MFMA16(af[kb].b, bf[0][kb].b, a0);
      a1 = MFMA16(af[kb].b, bf[1][kb].b, a1);
    }
    float bbv[4];
    *(float4*)bbv = *(const float4*)&b1[ncb * 16 + lg * 4];
    ushort h0[4], h1[4];
#pragma unroll
    for (int r = 0; r < 4; ++r) {
      h0[r] = f2bs(fmaxf(a0[r] + bbv[r], 0.f));
      h1[r] = f2bs(fmaxf(a1[r] + bbv[r], 0.f));
    }
    *(ushort4*)&hw[(0 * 16 + lr) * 132 + ncb * 16 + lg * 4] = *(ushort4*)h0;
    *(ushort4*)&hw[(1 * 16 + lr) * 132 + ncb * 16 + lg * 4] = *(ushort4*)h1;
  }

  // GEMM2: A = padded W2^T (16x128), B = h rows from LDS; 4 MFMA per m-tile
  union { uint4 u; bf16x8 b; } af2[4];
#pragma unroll
  for (int kb = 0; kb < 4; ++kb)
    af2[kb].u = *(const uint4*)&pW2p[(kb * 64 + l) * 8];

#pragma unroll
  for (int mt = 0; mt < 2; ++mt) {
    union { uint4 u; bf16x8 b; } bf2[4];
#pragma unroll
    for (int kb = 0; kb < 4; ++kb)
      bf2[kb].u = *(const uint4*)&hw[(mt * 16 + lr) * 132 + kb * 32 + lg * 8];
    f32x4 a2 = (f32x4){0.f, 0.f, 0.f, 0.f};
#pragma unroll
    for (int kb = 0; kb < 4; ++kb)
      a2 = MFMA16(af2[kb].b, bf2[kb].b, a2);
    if (lg < 2) {  // c2 = lg*4+r in [0,8)
      float bbv[4];
      *(float4*)bbv = *(const float4*)&b2[lg * 4];
      ushort s[4];
#pragma unroll
      for (int r = 0; r < 4; ++r) s[r] = f2bs(a2[r] + bbv[r]);
      *(ushort4*)&fv16[(size_t)(n0 + mt * 16 + lr) * 8 + lg * 4] = *(ushort4*)s;
    }
  }
}

// ------- Kernel 2 (MFMA, lane-parallel gathers): pairs + y = relu(x16@W0+b0) bf16;
//         block-reduced segsum1; boundary rows via tile-local 2nd accumulator. -------
__global__ __launch_bounds__(256) void k_pairs(
    const ushort* __restrict__ fv16, const int* __restrict__ edge_index,
    const int* __restrict__ didx, const int* __restrict__ batch,
    const ushort* __restrict__ pW0p, const float* __restrict__ b0,
    ushort* __restrict__ y, float* __restrict__ sums1) {
  __shared__ float ps[4][64];
  __shared__ int pg[4];
  const int t = threadIdx.x, wv = t >> 6, l = t & 63;
  const int lr = l & 15, lg = l >> 4, c0 = lg * 4;
  const int nbase = blockIdx.x * 512;

  union U { uint4 u; bf16x8 b; };
  U af[4];
#pragma unroll
  for (int ncb = 0; ncb < 4; ++ncb)
    af[ncb].u = *(const uint4*)&pW0p[(ncb * 64 + l) * 8];

  for (int tile = 0; tile < 4; ++tile) {
    const int n0 = nbase + tile * 128 + wv * 32;
    if (n0 < NNODES) {
      U bf[2];
      int gN[2];
#pragma unroll
      for (int mt = 0; mt < 2; ++mt) {
        const int n = n0 + mt * 16 + lr;
        gN[mt] = batch[n];
        bf[mt].u = make_uint4(0u, 0u, 0u, 0u);
        if (lg < 2) {
          const int de = didx[n];
          const int u = edge_index[de];
          const int v = edge_index[NEDGES + de];
          ushort4 bb = *(const ushort4*)&fv16[(size_t)n * 8 + lg * 4];
          ushort4 ub = *(const ushort4*)&fv16[(size_t)u * 8 + lg * 4];
          ushort4 vb = *(const ushort4*)&fv16[(size_t)v * 8 + lg * 4];
          const ushort* bp = (const ushort*)&bb;
          const ushort* up = (const ushort*)&ub;
          const ushort* vp = (const ushort*)&vb;
          ushort s[8];
#pragma unroll
          for (int j = 0; j < 4; ++j) {
            s[2 * j] = bp[j];
            float uf = __uint_as_float((unsigned)up[j] << 16);
            float vf = __uint_as_float((unsigned)vp[j] << 16);
            s[2 * j + 1] = (uf > vf) ? up[j] : vp[j];
          }
          bf[mt].u = *(uint4*)s;
        }
      }

      f32x4 acc[2][4];
#pragma unroll
      for (int mt = 0; mt < 2; ++mt)
#pragma unroll
        for (int ncb = 0; ncb < 4; ++ncb) {
          acc[mt][ncb] = (f32x4){0.f, 0.f, 0.f, 0.f};
          acc[mt][ncb] = MFMA16(af[ncb].b, bf[mt].b, acc[mt][ncb]);
        }

      const int g_first = __shfl(gN[0], 0);
      const int g_last  = __shfl(gN[1], 15);
      const bool bnd = (g_last != g_first);
      float wsum[4][4], np[4][4];
#pragma unroll
      for (int ncb = 0; ncb < 4; ++ncb)
#pragma unroll
        for (int r = 0; r < 4; ++r) { wsum[ncb][r] = 0.f; np[ncb][r] = 0.f; }

#pragma unroll
      for (int mt = 0; mt < 2; ++mt) {
        const int n = n0 + mt * 16 + lr;
        const int g = gN[mt];
#pragma unroll
        for (int ncb = 0; ncb < 4; ++ncb) {
          const int c = ncb * 16 + c0;
          float bbv[4];
          *(float4*)bbv = *(const float4*)&b0[c];
          ushort st[4];
#pragma unroll
          for (int r = 0; r < 4; ++r) {
            float v = fmaxf(acc[mt][ncb][r] + bbv[r], 0.f);
            st[r] = f2bs(v);
            if (g == g_first) wsum[ncb][r] += v;
            else if (g == g_last) np[ncb][r] += v;
            else atomicAdd(&sums1[g * 64 + c + r], v);  // ~never
          }
          *(ushort4*)&y[(size_t)n * 64 + c] = *(ushort4*)st;
        }
      }
#pragma unroll
      for (int ncb = 0; ncb < 4; ++ncb)
#pragma unroll
        for (int r = 0; r < 4; ++r) {
          float w = wsum[ncb][r];
          w += __shfl_xor(w, 1); w += __shfl_xor(w, 2);
          w += __shfl_xor(w, 4); w += __shfl_xor(w, 8);
          if (lr == 0) ps[wv][ncb * 16 + c0 + r] = w;
        }
      if (l == 0) pg[wv] = g_first;
      if (bnd) {
#pragma unroll
        for (int ncb = 0; ncb < 4; ++ncb)
#pragma unroll
          for (int r = 0; r < 4; ++r) {
            float w = np[ncb][r];
            w += __shfl_xor(w, 1); w += __shfl_xor(w, 2);
            w += __shfl_xor(w, 4); w += __shfl_xor(w, 8);
            if (lr == 0) atomicAdd(&sums1[g_last * 64 + ncb * 16 + c0 + r], w);
          }
      }
    } else {
      ps[wv][l] = 0.f;
      if (l == 0) pg[wv] = -1;
    }
    __syncthreads();

    if (t < 64) {
      const int bg = pg[0];
      float s = 0.f;
#pragma unroll
      for (int w = 0; w < 4; ++w) {
        const int gv = pg[w];
        if (gv < 0) continue;
        if (gv == bg) s += ps[w][t];
        else atomicAdd(&sums1[gv * 64 + t], ps[w][t]);
      }
      if (bg >= 0) atomicAdd(&sums1[bg * 64 + t], s);
    }
    __syncthreads();
  }
}

// ---------- xm = (sums/max(cnt,1)) @ LW  (D = 64 or 128) ----------
template <int D>
__global__ void k_meanlin(const float* __restrict__ sums,
                          const int* __restrict__ cnt,
                          const float* __restrict__ LW,
                          float* __restrict__ xm) {
  __shared__ float m[64];
  const int g = blockIdx.x, t = threadIdx.x;
  const float c = fmaxf((float)cnt[g], 1.f);
  if (t < 64) m[t] = sums[g * 64 + t] / c;
  __syncthreads();
  float a = 0.f;
#pragma unroll
  for (int k = 0; k < 64; ++k) a = fmaf(m[k], LW[k * D + t], a);
  xm[g * D + t] = a;
}

// ---- Kernel 4 (MFMA, 4 tiles/block): y2 = relu(y@g1W+g1b-xm1[g]) bf16;
//      block-reduced segsum2; boundary rows via tile-local 2nd accumulator ----
__global__ __launch_bounds__(256) void k_ds1(
    const ushort* __restrict__ ybf, const int* __restrict__ batch,
    const ushort* __restrict__ pW1, const float* __restrict__ g1b,
    const float* __restrict__ xm1, ushort* __restrict__ y2,
    float* __restrict__ sums2) {
  __shared__ float ps[4][64];
  __shared__ int pg[4];
  const int t = threadIdx.x, wv = t >> 6, l = t & 63;
  const int lr = l & 15, lg = l >> 4, c0 = lg * 4;
  const int nbase = blockIdx.x * 512;

  union U { uint4 u; bf16x8 b; };
  U af[4][2];
#pragma unroll
  for (int ncb = 0; ncb < 4; ++ncb)
#pragma unroll
    for (int kb = 0; kb < 2; ++kb)
      af[ncb][kb].u = *(const uint4*)&pW1[((ncb * 2 + kb) * 64 + l) * 8];

  for (int tile = 0; tile < 4; ++tile) {
    const int n0 = nbase + tile * 128 + wv * 32;
    if (n0 < NNODES) {
      U bf[2][2];
#pragma unroll
      for (int mt = 0; mt < 2; ++mt)
#pragma unroll
        for (int kb = 0; kb < 2; ++kb)
          bf[mt][kb].u = *(const uint4*)&ybf[(size_t)(n0 + mt * 16 + lr) * 64 + kb * 32 + lg * 8];

      f32x4 acc[2][4];
#pragma unroll
      for (int mt = 0; mt < 2; ++mt)
#pragma unroll
        for (int ncb = 0; ncb < 4; ++ncb) {
          acc[mt][ncb] = (f32x4){0.f, 0.f, 0.f, 0.f};
          acc[mt][ncb] = MFMA16(af[ncb][0].b, bf[mt][0].b, acc[mt][ncb]);
          acc[mt][ncb] = MFMA16(af[ncb][1].b, bf[mt][1].b, acc[mt][ncb]);
        }

      const int g0 = batch[n0 + lr], g1 = batch[n0 + 16 + lr];
      const int g_first = __shfl(g0, 0);
      const int g_last  = __shfl(g1, 15);
      const bool bnd = (g_last != g_first);

      float wsum[4][4], np[4][4];
#pragma unroll
      for (int ncb = 0; ncb < 4; ++ncb)
#pragma unroll
        for (int r = 0; r < 4; ++r) { wsum[ncb][r] = 0.f; np[ncb][r] = 0.f; }

#pragma unroll
      for (int mt = 0; mt < 2; ++mt) {
        const int n = n0 + mt * 16 + lr;
        const int g = mt ? g1 : g0;
#pragma unroll
        for (int ncb = 0; ncb < 4; ++ncb) {
          const int c = ncb * 16 + c0;
          float xmv[4], bbv[4];
          *(float4*)xmv = *(const float4*)&xm1[g * 64 + c];
          *(float4*)bbv = *(const float4*)&g1b[c];
          ushort st[4];
#pragma unroll
          for (int r = 0; r < 4; ++r) {
            float v = fmaxf(acc[mt][ncb][r] + bbv[r] - xmv[r], 0.f);
            st[r] = f2bs(v);
            if (g == g_first) wsum[ncb][r] += v;
            else if (g == g_last) np[ncb][r] += v;
            else atomicAdd(&sums2[g * 64 + c + r], v);  // ~never
          }
          *(ushort4*)&y2[(size_t)n * 64 + c] = *(ushort4*)st;
        }
      }
#pragma unroll
      for (int ncb = 0; ncb < 4; ++ncb)
#pragma unroll
        for (int r = 0; r < 4; ++r) {
          float w = wsum[ncb][r];
          w += __shfl_xor(w, 1); w += __shfl_xor(w, 2);
          w += __shfl_xor(w, 4); w += __shfl_xor(w, 8);
          if (lr == 0) ps[wv][ncb * 16 + c0 + r] = w;
        }
      if (l == 0) pg[wv] = g_first;
      if (bnd) {
#pragma unroll
        for (int ncb = 0; ncb < 4; ++ncb)
#pragma unroll
          for (int r = 0; r < 4; ++r) {
            float w = np[ncb][r];
            w += __shfl_xor(w, 1); w += __shfl_xor(w, 2);
            w += __shfl_xor(w, 4); w += __shfl_xor(w, 8);
            if (lr == 0) atomicAdd(&sums2[g_last * 64 + ncb * 16 + c0 + r], w);
          }
      }
    } else {
      ps[wv][l] = 0.f;
      if (l == 0) pg[wv] = -1;
    }
    __syncthreads();

    if (t < 64) {
      const int bg = pg[0];
      float s = 0.f;
#pragma unroll
      for (int w = 0; w < 4; ++w) {
        const int gv = pg[w];
        if (gv < 0) continue;
        if (gv == bg) s += ps[w][t];
        else atomicAdd(&sums2[gv * 64 + t], ps[w][t]);
      }
      if (bg >= 0) atomicAdd(&sums2[bg * 64 + t], s);
    }
    __syncthreads();
  }
}

// ---- Kernel 6a (MFMA, 4 tiles/block, register-accumulated BN stats) ----
__global__ __launch_bounds__(256) void k_ds2a(
    const ushort* __restrict__ y2, const int* __restrict__ batch,
    const ushort* __restrict__ pW2, const float* __restrict__ g2b,
    const float* __restrict__ xm2,
    float* __restrict__ pmu, float* __restrict__ psq) {
  __shared__ float ps[4][128], pq[4][128];
  const int t = threadIdx.x, wv = t >> 6, l = t & 63;
  const int lr = l & 15, lg = l >> 4, c0 = lg * 4;
  const int nbase = blockIdx.x * 512;

  float sw[8][4], sq[8][4];
#pragma unroll
  for (int ncb = 0; ncb < 8; ++ncb)
#pragma unroll
    for (int r = 0; r < 4; ++r) { sw[ncb][r] = 0.f; sq[ncb][r] = 0.f; }

  for (int tile = 0; tile < 4; ++tile) {
    const int n0 = nbase + tile * 128 + wv * 32;
    if (n0 >= NNODES) continue;

    union { uint4 u; bf16x8 b; } bf[2][2];
#pragma unroll
    for (int mt = 0; mt < 2; ++mt)
#pragma unroll
      for (int kb = 0; kb < 2; ++kb)
        bf[mt][kb].u = *(const uint4*)&y2[(size_t)(n0 + mt * 16 + lr) * 64 + kb * 32 + lg * 8];

    const int g0 = batch[n0 + lr], g1 = batch[n0 + 16 + lr];

#pragma unroll
    for (int ncb = 0; ncb < 8; ++ncb) {
      union { uint4 u; bf16x8 b; } af0, af1;
      af0.u = *(const uint4*)&pW2[((ncb * 2 + 0) * 64 + l) * 8];
      af1.u = *(const uint4*)&pW2[((ncb * 2 + 1) * 64 + l) * 8];
      f32x4 a0 = (f32x4){0.f, 0.f, 0.f, 0.f}, a1 = (f32x4){0.f, 0.f, 0.f, 0.f};
      a0 = MFMA16(af0.b, bf[0][0].b, a0); a0 = MFMA16(af1.b, bf[0][1].b, a0);
      a1 = MFMA16(af0.b, bf[1][0].b, a1); a1 = MFMA16(af1.b, bf[1][1].b, a1);

      const int c = ncb * 16 + c0;
      float xm0[4], xm1v[4], bbv[4];
      *(float4*)xm0 = *(const float4*)&xm2[g0 * 128 + c];
      *(float4*)xm1v = *(const float4*)&xm2[g1 * 128 + c];
      *(float4*)bbv = *(const float4*)&g2b[c];
#pragma unroll
      for (int r = 0; r < 4; ++r) {
        float v0 = fmaxf(a0[r] + bbv[r] - xm0[r], 0.f);
        float v1 = fmaxf(a1[r] + bbv[r] - xm1v[r], 0.f);
        sw[ncb][r] += v0 + v1;
        sq[ncb][r] = fmaf(v0, v0, fmaf(v1, v1, sq[ncb][r]));
      }
    }
  }

#pragma unroll
  for (int ncb = 0; ncb < 8; ++ncb)
#pragma unroll
    for (int r = 0; r < 4; ++r) {
      float wr = sw[ncb][r], qr = sq[ncb][r];
      wr += __shfl_xor(wr, 1); wr += __shfl_xor(wr, 2);
      wr += __shfl_xor(wr, 4); wr += __shfl_xor(wr, 8);
      qr += __shfl_xor(qr, 1); qr += __shfl_xor(qr, 2);
      qr += __shfl_xor(qr, 4); qr += __shfl_xor(qr, 8);
      if (lr == 0) { ps[wv][ncb * 16 + c0 + r] = wr; pq[wv][ncb * 16 + c0 + r] = qr; }
    }
  __syncthreads();
  if (t < 128) {
    pmu[(size_t)blockIdx.x * 128 + t] = ps[0][t] + ps[1][t] + ps[2][t] + ps[3][t];
    psq[(size_t)blockIdx.x * 128 + t] = pq[0][t] + pq[1][t] + pq[2][t] + pq[3][t];
  }
}

// ---- reduce BN partials ----
__global__ void k_red(const float* __restrict__ pmu, const float* __restrict__ psq,
                      float* __restrict__ musum, float* __restrict__ sqsum) {
  const int f = threadIdx.x & 127;
  const bool mu = threadIdx.x < 128;
  const float* src = mu ? pmu : psq;
  float s = 0.f;
  for (int b = blockIdx.x; b < NBLK4; b += 32) s += src[(size_t)b * 128 + f];
  atomicAdd(mu ? &musum[f] : &sqsum[f], s);
}

// ---- Kernel 7 (MFMA fused): recompute h (f32), LDS stage, coalesced BN+residual ----
__global__ __launch_bounds__(256) void k_bn(
    const ushort* __restrict__ y2, const int* __restrict__ batch,
    const ushort* __restrict__ pW2, const float* __restrict__ g2b,
    const float* __restrict__ xm2, const float* __restrict__ x,
    const float* __restrict__ musum, const float* __restrict__ sqsum,
    const float* __restrict__ gamma, const float* __restrict__ beta,
    float* __restrict__ out) {
  __shared__ float vs[64 * 132];
  __shared__ float smu[128], ssc[128], sbe[128];
  const int t = threadIdx.x, wv = t >> 6, l = t & 63;
  const int lr = l & 15, lg = l >> 4, c0 = lg * 4;
  if (t < 128) {
    const float invN = 1.f / (float)NNODES;
    float m = musum[t] * invN;
    float v = sqsum[t] * invN - m * m;
    smu[t] = m;
    ssc[t] = rsqrtf(v + BN_EPS) * gamma[t];
    sbe[t] = beta[t];
  }
  const int nblk = blockIdx.x * 64;
  const int n0 = nblk + wv * 16;

  if (n0 < NNODES) {
    union { uint4 u; bf16x8 b; } bf[2];
#pragma unroll
    for (int kb = 0; kb < 2; ++kb)
      bf[kb].u = *(const uint4*)&y2[(size_t)(n0 + lr) * 64 + kb * 32 + lg * 8];

    const int g0 = batch[n0 + lr];
    const int row0 = wv * 16 + lr;

#pragma unroll
    for (int ncb = 0; ncb < 8; ++ncb) {
      union { uint4 u; bf16x8 b; } af0, af1;
      af0.u = *(const uint4*)&pW2[((ncb * 2 + 0) * 64 + l) * 8];
      af1.u = *(const uint4*)&pW2[((ncb * 2 + 1) * 64 + l) * 8];
      f32x4 a0 = (f32x4){0.f, 0.f, 0.f, 0.f};
      a0 = MFMA16(af0.b, bf[0].b, a0);
      a0 = MFMA16(af1.b, bf[1].b, a0);

      const int c = ncb * 16 + c0;
      float bbv[4], xm0[4], hvv[4];
      *(float4*)bbv = *(const float4*)&g2b[c];
      *(float4*)xm0 = *(const float4*)&xm2[g0 * 128 + c];
#pragma unroll
      for (int r = 0; r < 4; ++r)
        hvv[r] = fmaxf(a0[r] + bbv[r] - xm0[r], 0.f);
      *(float4*)&vs[row0 * 132 + c] = *(float4*)hvv;
    }
  }
  __syncthreads();

  const int rmax = NNODES - nblk;
  for (int i = t; i < 2048; i += 256) {
    const int row = i >> 5, c4 = (i & 31) * 4;
    if (row >= rmax) break;
    const int n = nblk + row;
    float hv[4], muv[4], scv[4], bev[4], xv[4], o[4];
    *(float4*)hv = *(const float4*)&vs[row * 132 + c4];
    *(float4*)muv = *(const float4*)&smu[c4];
    *(float4*)scv = *(const float4*)&ssc[c4];
    *(float4*)bev = *(const float4*)&sbe[c4];
    *(float4*)xv = *(const float4*)&x[(size_t)n * 128 + c4];
#pragma unroll
    for (int r = 0; r < 4; ++r)
      o[r] = xv[r] + (hv[r] - muv[r]) * scv[r] + bev[r];
    *(float4*)&out[(size_t)n * 128 + c4] = *(float4*)o;
  }
}

extern "C" void kernel_launch(void* const* d_in, const int* in_sizes, int n_in,
                              void* d_out, int out_size, void* d_ws,
                              size_t ws_size, hipStream_t stream) {
  const float* x     = (const float*)d_in[0];
  const float* W1    = (const float*)d_in[1];
  const float* b1    = (const float*)d_in[2];
  const float* W2    = (const float*)d_in[3];
  const float* b2    = (const float*)d_in[4];
  const float* W0    = (const float*)d_in[5];
  const float* b0    = (const float*)d_in[6];
  const float* g1W   = (const float*)d_in[7];
  const float* g1b   = (const float*)d_in[8];
  const float* l1W   = (const float*)d_in[9];
  const float* g2W   = (const float*)d_in[10];
  const float* g2b   = (const float*)d_in[11];
  const float* l2W   = (const float*)d_in[12];
  const float* gamma = (const float*)d_in[13];
  const float* beta  = (const float*)d_in[14];
  const int* edge_index = (const int*)d_in[15];
  const int* batch      = (const int*)d_in[16];
  const int* didx       = (const int*)d_in[17];
  float* out = (float*)d_out;

  char* ws = (char*)d_ws;
  ushort* fv16  = (ushort*)(ws + 0);           // 8,000,000 B (dead after k_pairs)
  float*  pmu   = (float*) (ws + 0);           // 500,224 B (reuses fv16)
  float*  psq   = (float*) (ws + 2000384);
  ushort* ybf   = (ushort*)(ws + 16000000);    // 64,000,000 B
  ushort* y2    = (ushort*)(ws + 80000000);    // 64,000,000 B
  float*  sums1 = (float*) (ws + 144000000);
  float*  sums2 = (float*) (ws + 144131072);
  float*  musum = (float*) (ws + 144262144);
  float*  sqsum = (float*) (ws + 144262656);
  int*    cnt   = (int*)   (ws + 144263168);
  float*  xm1   = (float*) (ws + 144265216);
  float*  xm2   = (float*) (ws + 144396288);
  ushort* pW1   = (ushort*)(ws + 144658432);
  ushort* pW2   = (ushort*)(ws + 144666624);
  ushort* pW0   = (ushort*)(ws + 144683008);   // 32,768 B
  ushort* pW0p  = (ushort*)(ws + 144715776);   // 8,192 B
  ushort* pW2p  = (ushort*)(ws + 144723968);   // 8,192 B (end 144,732,160)

  hipMemsetAsync(ws + 144000000, 0, 263168, stream);

  k_pack<<<64, 256, 0, stream>>>(g1W, g2W, W1, W0, W2, batch,
                                 pW1, pW2, pW0, pW0p, pW2p, cnt);
  k_filt<<<NBLK2, 256, 0, stream>>>(x, pW0, b1, pW2p, b2, fv16);
  k_pairs<<<NBLK4, 256, 0, stream>>>(fv16, edge_index, didx, batch, pW0p, b0, ybf, sums1);
  k_meanlin<64><<<NGRAPHS, 64, 0, stream>>>(sums1, cnt, l1W, xm1);
  k_ds1<<<NBLK4, 256, 0, stream>>>(ybf, batch, pW1, g1b, xm1, y2, sums2);
  k_meanlin<128><<<NGRAPHS, 128, 0, stream>>>(sums2, cnt, l2W, xm2);
  k_ds2a<<<NBLK4, 256, 0, stream>>>(y2, batch, pW2, g2b, xm2, pmu, psq);
  k_red<<<32, 256, 0, stream>>>(pmu, psq, musum, sqsum);
  k_bn<<<NBLK3, 256, 0, stream>>>(y2, batch, pW2, g2b, xm2, x, musum, sqsum,
                                  gamma, beta, out);
}

// Round 16
// 456.855 us; speedup vs baseline: 1.3650x; 1.0008x over previous
//
#include <hip/hip_runtime.h>
#include <hip/hip_bf16.h>

#define NNODES 500000
#define NEDGES 8000000
#define NGRAPHS 512
#define NFEAT 128
#define NHID 128
#define NFILT 8
#define ODIM 64
#define BN_EPS 1e-5f
#define NBLK2 3907  // ceil(NNODES/128)
#define NBLK3 7813  // ceil(NNODES/64)  for k_bn
#define NBLK4 977   // ceil(NNODES/512) for k_pairs/k_ds1/k_ds2a (4 tiles/block)

typedef __attribute__((ext_vector_type(8))) short bf16x8;
typedef __attribute__((ext_vector_type(4))) float f32x4;
#define MFMA16(a, b, c) __builtin_amdgcn_mfma_f32_16x16x32_bf16(a, b, c, 0, 0, 0)

__device__ inline ushort f2bs(float f) {
  union { __hip_bfloat16 h; ushort u; } cv;
  cv.h = __float2bfloat16(f);
  return cv.u;
}

// ---- pack weights into MFMA A-frag layout + cnt[g] + zero accumulators ----
__global__ void k_pack(const float* __restrict__ g1W, const float* __restrict__ g2W,
                       const float* __restrict__ W1, const float* __restrict__ W0,
                       const float* __restrict__ W2, const int* __restrict__ batch,
                       ushort* __restrict__ pW1, ushort* __restrict__ pW2,
                       ushort* __restrict__ pW0, ushort* __restrict__ pW0p,
                       ushort* __restrict__ pW2p, int* __restrict__ cnt,
                       float* __restrict__ zacc) {
  int idx = blockIdx.x * 256 + threadIdx.x;
  // zero sums1/sums2/musum/sqsum (contiguous 65,792 floats)
  for (int z = idx; z < 65792; z += 16384) zacc[z] = 0.f;
  if (idx < 4096) {
    int j = idx & 7, l = (idx >> 3) & 63, kb = (idx >> 9) & 1, ncb = idx >> 10;
    int k = kb * 32 + (l >> 4) * 8 + j, c = ncb * 16 + (l & 15);
    pW1[idx] = f2bs(g1W[k * 64 + c]);
  }
  if (idx < 8192) {
    int j = idx & 7, l = (idx >> 3) & 63, kb = (idx >> 9) & 1, ncb = idx >> 10;
    int k = kb * 32 + (l >> 4) * 8 + j, c = ncb * 16 + (l & 15);
    pW2[idx] = f2bs(g2W[k * 128 + c]);
  }
  if (idx < 16384) {
    int j = idx & 7, l = (idx >> 3) & 63, kb = (idx >> 9) & 3, ncb = idx >> 11;
    int k = kb * 32 + (l >> 4) * 8 + j, c = ncb * 16 + (l & 15);
    pW0[idx] = f2bs(W1[k * 128 + c]);
  }
  if (idx < 4096) {
    int j = idx & 7, l = (idx >> 3) & 63, ncb = idx >> 9;
    int k = (l >> 4) * 8 + j, c = ncb * 16 + (l & 15);
    pW0p[idx] = (k < 16) ? f2bs(W0[k * 64 + c]) : (ushort)0;
  }
  if (idx < 4096) {  // pW2p: W2 [128x8] -> A[m<16][k<128], zero-pad m>=8
    int j = idx & 7, l = (idx >> 3) & 63, kb = idx >> 9;
    int k = kb * 32 + (l >> 4) * 8 + j, m = l & 15;
    pW2p[idx] = (m < 8) ? f2bs(W2[k * 8 + m]) : (ushort)0;
  }
  if (idx < NGRAPHS) {
    int g = idx;
    int lo0 = 0, hi0 = NNODES;
    while (lo0 < hi0) { int mid = (lo0 + hi0) >> 1; if (batch[mid] < g) lo0 = mid + 1; else hi0 = mid; }
    int lo1 = lo0, hi1 = NNODES;
    while (lo1 < hi1) { int mid = (lo1 + hi1) >> 1; if (batch[mid] < g + 1) lo1 = mid + 1; else hi1 = mid; }
    cnt[g] = lo1 - lo0;
  }
}

// ---- Kernel 1 (all-MFMA): fv16 = bf16( relu(x@W1+b1)@W2 + b2 )  [N,8] ----
__global__ __launch_bounds__(256) void k_filt(
    const float* __restrict__ x, const ushort* __restrict__ pW0,
    const float* __restrict__ b1, const ushort* __restrict__ pW2p,
    const float* __restrict__ b2, ushort* __restrict__ fv16) {
  __shared__ ushort hs[4 * 32 * 132];  // wave-private 32x132 tiles
  const int t = threadIdx.x;
  const int wv = t >> 6, l = t & 63;
  const int lr = l & 15, lg = l >> 4;
  const int n0 = blockIdx.x * 128 + wv * 32;
  if (n0 >= NNODES) return;  // no barriers: wave-private LDS only
  ushort* hw = &hs[wv * 32 * 132];

  union { uint4 u; bf16x8 b; } bf[2][4];
#pragma unroll
  for (int mt = 0; mt < 2; ++mt)
#pragma unroll
    for (int kb = 0; kb < 4; ++kb) {
      const float* src = &x[(size_t)(n0 + mt * 16 + lr) * 128 + kb * 32 + lg * 8];
      float v[8];
      *(float4*)&v[0] = *(const float4*)src;
      *(float4*)&v[4] = *(const float4*)(src + 4);
      ushort s[8];
#pragma unroll
      for (int e = 0; e < 8; ++e) s[e] = f2bs(v[e]);
      bf[mt][kb].u = *(uint4*)s;
    }

#pragma unroll
  for (int ncb = 0; ncb < 8; ++ncb) {
    union { uint4 u; bf16x8 b; } af[4];
#pragma unroll
    for (int kb = 0; kb < 4; ++kb)
      af[kb].u = *(const uint4*)&pW0[((ncb * 4 + kb) * 64 + l) * 8];
    f32x4 a0 = (f32x4){0.f, 0.f, 0.f, 0.f};
    f32x4 a1 = (f32x4){0.f, 0.f, 0.f, 0.f};
#pragma unroll
    for (int kb = 0; kb < 4; ++kb) {
      a0 = MFMA16(af[kb].b, bf[0][kb].b, a0);
      a1 = MFMA16(af[kb].b, bf[1][kb].b, a1);
    }
    float bbv[4];
    *(float4*)bbv = *(const float4*)&b1[ncb * 16 + lg * 4];
    ushort h0[4], h1[4];
#pragma unroll
    for (int r = 0; r < 4; ++r) {
      h0[r] = f2bs(fmaxf(a0[r] + bbv[r], 0.f));
      h1[r] = f2bs(fmaxf(a1[r] + bbv[r], 0.f));
    }
    *(ushort4*)&hw[(0 * 16 + lr) * 132 + ncb * 16 + lg * 4] = *(ushort4*)h0;
    *(ushort4*)&hw[(1 * 16 + lr) * 132 + ncb * 16 + lg * 4] = *(ushort4*)h1;
  }

  union { uint4 u; bf16x8 b; } af2[4];
#pragma unroll
  for (int kb = 0; kb < 4; ++kb)
    af2[kb].u = *(const uint4*)&pW2p[(kb * 64 + l) * 8];

#pragma unroll
  for (int mt = 0; mt < 2; ++mt) {
    union { uint4 u; bf16x8 b; } bf2[4];
#pragma unroll
    for (int kb = 0; kb < 4; ++kb)
      bf2[kb].u = *(const uint4*)&hw[(mt * 16 + lr) * 132 + kb * 32 + lg * 8];
    f32x4 a2 = (f32x4){0.f, 0.f, 0.f, 0.f};
#pragma unroll
    for (int kb = 0; kb < 4; ++kb)
      a2 = MFMA16(af2[kb].b, bf2[kb].b, a2);
    if (lg < 2) {
      float bbv[4];
      *(float4*)bbv = *(const float4*)&b2[lg * 4];
      ushort s[4];
#pragma unroll
      for (int r = 0; r < 4; ++r) s[r] = f2bs(a2[r] + bbv[r]);
      *(ushort4*)&fv16[(size_t)(n0 + mt * 16 + lr) * 8 + lg * 4] = *(ushort4*)s;
    }
  }
}

// ------- Kernel 2 (MFMA, lane-parallel gathers): pairs + y = relu(x16@W0+b0) bf16;
//         block-reduced segsum1; boundary rows via tile-local 2nd accumulator. -------
__global__ __launch_bounds__(256) void k_pairs(
    const ushort* __restrict__ fv16, const int* __restrict__ edge_index,
    const int* __restrict__ didx, const int* __restrict__ batch,
    const ushort* __restrict__ pW0p, const float* __restrict__ b0,
    ushort* __restrict__ y, float* __restrict__ sums1) {
  __shared__ float ps[4][64];
  __shared__ int pg[4];
  const int t = threadIdx.x, wv = t >> 6, l = t & 63;
  const int lr = l & 15, lg = l >> 4, c0 = lg * 4;
  const int nbase = blockIdx.x * 512;

  union U { uint4 u; bf16x8 b; };
  U af[4];
#pragma unroll
  for (int ncb = 0; ncb < 4; ++ncb)
    af[ncb].u = *(const uint4*)&pW0p[(ncb * 64 + l) * 8];

  for (int tile = 0; tile < 4; ++tile) {
    const int n0 = nbase + tile * 128 + wv * 32;
    if (n0 < NNODES) {
      U bf[2];
      int gN[2];
#pragma unroll
      for (int mt = 0; mt < 2; ++mt) {
        const int n = n0 + mt * 16 + lr;
        gN[mt] = batch[n];
        bf[mt].u = make_uint4(0u, 0u, 0u, 0u);
        if (lg < 2) {
          const int de = didx[n];
          const int u = edge_index[de];
          const int v = edge_index[NEDGES + de];
          ushort4 bb = *(const ushort4*)&fv16[(size_t)n * 8 + lg * 4];
          ushort4 ub = *(const ushort4*)&fv16[(size_t)u * 8 + lg * 4];
          ushort4 vb = *(const ushort4*)&fv16[(size_t)v * 8 + lg * 4];
          const ushort* bp = (const ushort*)&bb;
          const ushort* up = (const ushort*)&ub;
          const ushort* vp = (const ushort*)&vb;
          ushort s[8];
#pragma unroll
          for (int j = 0; j < 4; ++j) {
            s[2 * j] = bp[j];
            float uf = __uint_as_float((unsigned)up[j] << 16);
            float vf = __uint_as_float((unsigned)vp[j] << 16);
            s[2 * j + 1] = (uf > vf) ? up[j] : vp[j];
          }
          bf[mt].u = *(uint4*)s;
        }
      }

      f32x4 acc[2][4];
#pragma unroll
      for (int mt = 0; mt < 2; ++mt)
#pragma unroll
        for (int ncb = 0; ncb < 4; ++ncb) {
          acc[mt][ncb] = (f32x4){0.f, 0.f, 0.f, 0.f};
          acc[mt][ncb] = MFMA16(af[ncb].b, bf[mt].b, acc[mt][ncb]);
        }

      const int g_first = __shfl(gN[0], 0);
      const int g_last  = __shfl(gN[1], 15);
      const bool bnd = (g_last != g_first);
      float wsum[4][4], np[4][4];
#pragma unroll
      for (int ncb = 0; ncb < 4; ++ncb)
#pragma unroll
        for (int r = 0; r < 4; ++r) { wsum[ncb][r] = 0.f; np[ncb][r] = 0.f; }

#pragma unroll
      for (int mt = 0; mt < 2; ++mt) {
        const int n = n0 + mt * 16 + lr;
        const int g = gN[mt];
#pragma unroll
        for (int ncb = 0; ncb < 4; ++ncb) {
          const int c = ncb * 16 + c0;
          float bbv[4];
          *(float4*)bbv = *(const float4*)&b0[c];
          ushort st[4];
#pragma unroll
          for (int r = 0; r < 4; ++r) {
            float v = fmaxf(acc[mt][ncb][r] + bbv[r], 0.f);
            st[r] = f2bs(v);
            if (g == g_first) wsum[ncb][r] += v;
            else if (g == g_last) np[ncb][r] += v;
            else atomicAdd(&sums1[g * 64 + c + r], v);  // ~never
          }
          *(ushort4*)&y[(size_t)n * 64 + c] = *(ushort4*)st;
        }
      }
#pragma unroll
      for (int ncb = 0; ncb < 4; ++ncb)
#pragma unroll
        for (int r = 0; r < 4; ++r) {
          float w = wsum[ncb][r];
          w += __shfl_xor(w, 1); w += __shfl_xor(w, 2);
          w += __shfl_xor(w, 4); w += __shfl_xor(w, 8);
          if (lr == 0) ps[wv][ncb * 16 + c0 + r] = w;
        }
      if (l == 0) pg[wv] = g_first;
      if (bnd) {
#pragma unroll
        for (int ncb = 0; ncb < 4; ++ncb)
#pragma unroll
          for (int r = 0; r < 4; ++r) {
            float w = np[ncb][r];
            w += __shfl_xor(w, 1); w += __shfl_xor(w, 2);
            w += __shfl_xor(w, 4); w += __shfl_xor(w, 8);
            if (lr == 0) atomicAdd(&sums1[g_last * 64 + ncb * 16 + c0 + r], w);
          }
      }
    } else {
      ps[wv][l] = 0.f;
      if (l == 0) pg[wv] = -1;
    }
    __syncthreads();

    if (t < 64) {
      const int bg = pg[0];
      float s = 0.f;
#pragma unroll
      for (int w = 0; w < 4; ++w) {
        const int gv = pg[w];
        if (gv < 0) continue;
        if (gv == bg) s += ps[w][t];
        else atomicAdd(&sums1[gv * 64 + t], ps[w][t]);
      }
      if (bg >= 0) atomicAdd(&sums1[bg * 64 + t], s);
    }
    __syncthreads();
  }
}

// ---------- xm = (sums/max(cnt,1)) @ LW  (D = 64 or 128) ----------
template <int D>
__global__ void k_meanlin(const float* __restrict__ sums,
                          const int* __restrict__ cnt,
                          const float* __restrict__ LW,
                          float* __restrict__ xm) {
  __shared__ float m[64];
  const int g = blockIdx.x, t = threadIdx.x;
  const float c = fmaxf((float)cnt[g], 1.f);
  if (t < 64) m[t] = sums[g * 64 + t] / c;
  __syncthreads();
  float a = 0.f;
#pragma unroll
  for (int k = 0; k < 64; ++k) a = fmaf(m[k], LW[k * D + t], a);
  xm[g * D + t] = a;
}

// ---- Kernel 4 (MFMA, 4 tiles/block): y2 = relu(y@g1W+g1b-xm1[g]) bf16;
//      block-reduced segsum2; boundary rows via tile-local 2nd accumulator ----
__global__ __launch_bounds__(256) void k_ds1(
    const ushort* __restrict__ ybf, const int* __restrict__ batch,
    const ushort* __restrict__ pW1, const float* __restrict__ g1b,
    const float* __restrict__ xm1, ushort* __restrict__ y2,
    float* __restrict__ sums2) {
  __shared__ float ps[4][64];
  __shared__ int pg[4];
  const int t = threadIdx.x, wv = t >> 6, l = t & 63;
  const int lr = l & 15, lg = l >> 4, c0 = lg * 4;
  const int nbase = blockIdx.x * 512;

  union U { uint4 u; bf16x8 b; };
  U af[4][2];
#pragma unroll
  for (int ncb = 0; ncb < 4; ++ncb)
#pragma unroll
    for (int kb = 0; kb < 2; ++kb)
      af[ncb][kb].u = *(const uint4*)&pW1[((ncb * 2 + kb) * 64 + l) * 8];

  for (int tile = 0; tile < 4; ++tile) {
    const int n0 = nbase + tile * 128 + wv * 32;
    if (n0 < NNODES) {
      U bf[2][2];
#pragma unroll
      for (int mt = 0; mt < 2; ++mt)
#pragma unroll
        for (int kb = 0; kb < 2; ++kb)
          bf[mt][kb].u = *(const uint4*)&ybf[(size_t)(n0 + mt * 16 + lr) * 64 + kb * 32 + lg * 8];

      f32x4 acc[2][4];
#pragma unroll
      for (int mt = 0; mt < 2; ++mt)
#pragma unroll
        for (int ncb = 0; ncb < 4; ++ncb) {
          acc[mt][ncb] = (f32x4){0.f, 0.f, 0.f, 0.f};
          acc[mt][ncb] = MFMA16(af[ncb][0].b, bf[mt][0].b, acc[mt][ncb]);
          acc[mt][ncb] = MFMA16(af[ncb][1].b, bf[mt][1].b, acc[mt][ncb]);
        }

      const int g0 = batch[n0 + lr], g1 = batch[n0 + 16 + lr];
      const int g_first = __shfl(g0, 0);
      const int g_last  = __shfl(g1, 15);
      const bool bnd = (g_last != g_first);

      float wsum[4][4], np[4][4];
#pragma unroll
      for (int ncb = 0; ncb < 4; ++ncb)
#pragma unroll
        for (int r = 0; r < 4; ++r) { wsum[ncb][r] = 0.f; np[ncb][r] = 0.f; }

#pragma unroll
      for (int mt = 0; mt < 2; ++mt) {
        const int n = n0 + mt * 16 + lr;
        const int g = mt ? g1 : g0;
#pragma unroll
        for (int ncb = 0; ncb < 4; ++ncb) {
          const int c = ncb * 16 + c0;
          float xmv[4], bbv[4];
          *(float4*)xmv = *(const float4*)&xm1[g * 64 + c];
          *(float4*)bbv = *(const float4*)&g1b[c];
          ushort st[4];
#pragma unroll
          for (int r = 0; r < 4; ++r) {
            float v = fmaxf(acc[mt][ncb][r] + bbv[r] - xmv[r], 0.f);
            st[r] = f2bs(v);
            if (g == g_first) wsum[ncb][r] += v;
            else if (g == g_last) np[ncb][r] += v;
            else atomicAdd(&sums2[g * 64 + c + r], v);  // ~never
          }
          *(ushort4*)&y2[(size_t)n * 64 + c] = *(ushort4*)st;
        }
      }
#pragma unroll
      for (int ncb = 0; ncb < 4; ++ncb)
#pragma unroll
        for (int r = 0; r < 4; ++r) {
          float w = wsum[ncb][r];
          w += __shfl_xor(w, 1); w += __shfl_xor(w, 2);
          w += __shfl_xor(w, 4); w += __shfl_xor(w, 8);
          if (lr == 0) ps[wv][ncb * 16 + c0 + r] = w;
        }
      if (l == 0) pg[wv] = g_first;
      if (bnd) {
#pragma unroll
        for (int ncb = 0; ncb < 4; ++ncb)
#pragma unroll
          for (int r = 0; r < 4; ++r) {
            float w = np[ncb][r];
            w += __shfl_xor(w, 1); w += __shfl_xor(w, 2);
            w += __shfl_xor(w, 4); w += __shfl_xor(w, 8);
            if (lr == 0) atomicAdd(&sums2[g_last * 64 + ncb * 16 + c0 + r], w);
          }
      }
    } else {
      ps[wv][l] = 0.f;
      if (l == 0) pg[wv] = -1;
    }
    __syncthreads();

    if (t < 64) {
      const int bg = pg[0];
      float s = 0.f;
#pragma unroll
      for (int w = 0; w < 4; ++w) {
        const int gv = pg[w];
        if (gv < 0) continue;
        if (gv == bg) s += ps[w][t];
        else atomicAdd(&sums2[gv * 64 + t], ps[w][t]);
      }
      if (bg >= 0) atomicAdd(&sums2[bg * 64 + t], s);
    }
    __syncthreads();
  }
}

// ---- Kernel 6a (MFMA, 4 tiles/block, register BN stats, direct atomics) ----
__global__ __launch_bounds__(256) void k_ds2a(
    const ushort* __restrict__ y2, const int* __restrict__ batch,
    const ushort* __restrict__ pW2, const float* __restrict__ g2b,
    const float* __restrict__ xm2,
    float* __restrict__ musum, float* __restrict__ sqsum) {
  __shared__ float ps[4][128], pq[4][128];
  const int t = threadIdx.x, wv = t >> 6, l = t & 63;
  const int lr = l & 15, lg = l >> 4, c0 = lg * 4;
  const int nbase = blockIdx.x * 512;

  float sw[8][4], sq[8][4];
#pragma unroll
  for (int ncb = 0; ncb < 8; ++ncb)
#pragma unroll
    for (int r = 0; r < 4; ++r) { sw[ncb][r] = 0.f; sq[ncb][r] = 0.f; }

  for (int tile = 0; tile < 4; ++tile) {
    const int n0 = nbase + tile * 128 + wv * 32;
    if (n0 >= NNODES) continue;

    union { uint4 u; bf16x8 b; } bf[2][2];
#pragma unroll
    for (int mt = 0; mt < 2; ++mt)
#pragma unroll
      for (int kb = 0; kb < 2; ++kb)
        bf[mt][kb].u = *(const uint4*)&y2[(size_t)(n0 + mt * 16 + lr) * 64 + kb * 32 + lg * 8];

    const int g0 = batch[n0 + lr], g1 = batch[n0 + 16 + lr];

#pragma unroll
    for (int ncb = 0; ncb < 8; ++ncb) {
      union { uint4 u; bf16x8 b; } af0, af1;
      af0.u = *(const uint4*)&pW2[((ncb * 2 + 0) * 64 + l) * 8];
      af1.u = *(const uint4*)&pW2[((ncb * 2 + 1) * 64 + l) * 8];
      f32x4 a0 = (f32x4){0.f, 0.f, 0.f, 0.f}, a1 = (f32x4){0.f, 0.f, 0.f, 0.f};
      a0 = MFMA16(af0.b, bf[0][0].b, a0); a0 = MFMA16(af1.b, bf[0][1].b, a0);
      a1 = MFMA16(af0.b, bf[1][0].b, a1); a1 = MFMA16(af1.b, bf[1][1].b, a1);

      const int c = ncb * 16 + c0;
      float xm0[4], xm1v[4], bbv[4];
      *(float4*)xm0 = *(const float4*)&xm2[g0 * 128 + c];
      *(float4*)xm1v = *(const float4*)&xm2[g1 * 128 + c];
      *(float4*)bbv = *(const float4*)&g2b[c];
#pragma unroll
      for (int r = 0; r < 4; ++r) {
        float v0 = fmaxf(a0[r] + bbv[r] - xm0[r], 0.f);
        float v1 = fmaxf(a1[r] + bbv[r] - xm1v[r], 0.f);
        sw[ncb][r] += v0 + v1;
        sq[ncb][r] = fmaf(v0, v0, fmaf(v1, v1, sq[ncb][r]));
      }
    }
  }

#pragma unroll
  for (int ncb = 0; ncb < 8; ++ncb)
#pragma unroll
    for (int r = 0; r < 4; ++r) {
      float wr = sw[ncb][r], qr = sq[ncb][r];
      wr += __shfl_xor(wr, 1); wr += __shfl_xor(wr, 2);
      wr += __shfl_xor(wr, 4); wr += __shfl_xor(wr, 8);
      qr += __shfl_xor(qr, 1); qr += __shfl_xor(qr, 2);
      qr += __shfl_xor(qr, 4); qr += __shfl_xor(qr, 8);
      if (lr == 0) { ps[wv][ncb * 16 + c0 + r] = wr; pq[wv][ncb * 16 + c0 + r] = qr; }
    }
  __syncthreads();
  if (t < 128) {
    atomicAdd(&musum[t], ps[0][t] + ps[1][t] + ps[2][t] + ps[3][t]);
    atomicAdd(&sqsum[t], pq[0][t] + pq[1][t] + pq[2][t] + pq[3][t]);
  }
}

// ---- Kernel 7 (MFMA fused): recompute h (f32), LDS stage, coalesced BN+residual ----
__global__ __launch_bounds__(256) void k_bn(
    const ushort* __restrict__ y2, const int* __restrict__ batch,
    const ushort* __restrict__ pW2, const float* __restrict__ g2b,
    const float* __restrict__ xm2, const float* __restrict__ x,
    const float* __restrict__ musum, const float* __restrict__ sqsum,
    const float* __restrict__ gamma, const float* __restrict__ beta,
    float* __restrict__ out) {
  __shared__ float vs[64 * 132];
  __shared__ float smu[128], ssc[128], sbe[128];
  const int t = threadIdx.x, wv = t >> 6, l = t & 63;
  const int lr = l & 15, lg = l >> 4, c0 = lg * 4;
  if (t < 128) {
    const float invN = 1.f / (float)NNODES;
    float m = musum[t] * invN;
    float v = sqsum[t] * invN - m * m;
    smu[t] = m;
    ssc[t] = rsqrtf(v + BN_EPS) * gamma[t];
    sbe[t] = beta[t];
  }
  const int nblk = blockIdx.x * 64;
  const int n0 = nblk + wv * 16;

  if (n0 < NNODES) {
    union { uint4 u; bf16x8 b; } bf[2];
#pragma unroll
    for (int kb = 0; kb < 2; ++kb)
      bf[kb].u = *(const uint4*)&y2[(size_t)(n0 + lr) * 64 + kb * 32 + lg * 8];

    const int g0 = batch[n0 + lr];
    const int row0 = wv * 16 + lr;

#pragma unroll
    for (int ncb = 0; ncb < 8; ++ncb) {
      union { uint4 u; bf16x8 b; } af0, af1;
      af0.u = *(const uint4*)&pW2[((ncb * 2 + 0) * 64 + l) * 8];
      af1.u = *(const uint4*)&pW2[((ncb * 2 + 1) * 64 + l) * 8];
      f32x4 a0 = (f32x4){0.f, 0.f, 0.f, 0.f};
      a0 = MFMA16(af0.b, bf[0].b, a0);
      a0 = MFMA16(af1.b, bf[1].b, a0);

      const int c = ncb * 16 + c0;
      float bbv[4], xm0[4], hvv[4];
      *(float4*)bbv = *(const float4*)&g2b[c];
      *(float4*)xm0 = *(const float4*)&xm2[g0 * 128 + c];
#pragma unroll
      for (int r = 0; r < 4; ++r)
        hvv[r] = fmaxf(a0[r] + bbv[r] - xm0[r], 0.f);
      *(float4*)&vs[row0 * 132 + c] = *(float4*)hvv;
    }
  }
  __syncthreads();

  const int rmax = NNODES - nblk;
  for (int i = t; i < 2048; i += 256) {
    const int row = i >> 5, c4 = (i & 31) * 4;
    if (row >= rmax) break;
    const int n = nblk + row;
    float hv[4], muv[4], scv[4], bev[4], xv[4], o[4];
    *(float4*)hv = *(const float4*)&vs[row * 132 + c4];
    *(float4*)muv = *(const float4*)&smu[c4];
    *(float4*)scv = *(const float4*)&ssc[c4];
    *(float4*)bev = *(const float4*)&sbe[c4];
    *(float4*)xv = *(const float4*)&x[(size_t)n * 128 + c4];
#pragma unroll
    for (int r = 0; r < 4; ++r)
      o[r] = xv[r] + (hv[r] - muv[r]) * scv[r] + bev[r];
    *(float4*)&out[(size_t)n * 128 + c4] = *(float4*)o;
  }
}

extern "C" void kernel_launch(void* const* d_in, const int* in_sizes, int n_in,
                              void* d_out, int out_size, void* d_ws,
                              size_t ws_size, hipStream_t stream) {
  const float* x     = (const float*)d_in[0];
  const float* W1    = (const float*)d_in[1];
  const float* b1    = (const float*)d_in[2];
  const float* W2    = (const float*)d_in[3];
  const float* b2    = (const float*)d_in[4];
  const float* W0    = (const float*)d_in[5];
  const float* b0    = (const float*)d_in[6];
  const float* g1W   = (const float*)d_in[7];
  const float* g1b   = (const float*)d_in[8];
  const float* l1W   = (const float*)d_in[9];
  const float* g2W   = (const float*)d_in[10];
  const float* g2b   = (const float*)d_in[11];
  const float* l2W   = (const float*)d_in[12];
  const float* gamma = (const float*)d_in[13];
  const float* beta  = (const float*)d_in[14];
  const int* edge_index = (const int*)d_in[15];
  const int* batch      = (const int*)d_in[16];
  const int* didx       = (const int*)d_in[17];
  float* out = (float*)d_out;

  char* ws = (char*)d_ws;
  ushort* fv16  = (ushort*)(ws + 0);           // 8,000,000 B (dead after k_pairs)
  ushort* ybf   = (ushort*)(ws + 16000000);    // 64,000,000 B
  ushort* y2    = (ushort*)(ws + 80000000);    // 64,000,000 B
  float*  zacc  = (float*) (ws + 144000000);   // sums1..sqsum contiguous
  float*  sums1 = (float*) (ws + 144000000);
  float*  sums2 = (float*) (ws + 144131072);
  float*  musum = (float*) (ws + 144262144);
  float*  sqsum = (float*) (ws + 144262656);
  int*    cnt   = (int*)   (ws + 144263168);
  float*  xm1   = (float*) (ws + 144265216);
  float*  xm2   = (float*) (ws + 144396288);
  ushort* pW1   = (ushort*)(ws + 144658432);
  ushort* pW2   = (ushort*)(ws + 144666624);
  ushort* pW0   = (ushort*)(ws + 144683008);   // 32,768 B
  ushort* pW0p  = (ushort*)(ws + 144715776);   // 8,192 B
  ushort* pW2p  = (ushort*)(ws + 144723968);   // 8,192 B (end 144,732,160)

  k_pack<<<64, 256, 0, stream>>>(g1W, g2W, W1, W0, W2, batch,
                                 pW1, pW2, pW0, pW0p, pW2p, cnt, zacc);
  k_filt<<<NBLK2, 256, 0, stream>>>(x, pW0, b1, pW2p, b2, fv16);
  k_pairs<<<NBLK4, 256, 0, stream>>>(fv16, edge_index, didx, batch, pW0p, b0, ybf, sums1);
  k_meanlin<64><<<NGRAPHS, 64, 0, stream>>>(sums1, cnt, l1W, xm1);
  k_ds1<<<NBLK4, 256, 0, stream>>>(ybf, batch, pW1, g1b, xm1, y2, sums2);
  k_meanlin<128><<<NGRAPHS, 128, 0, stream>>>(sums2, cnt, l2W, xm2);
  k_ds2a<<<NBLK4, 256, 0, stream>>>(y2, batch, pW2, g2b, xm2, musum, sqsum);
  k_bn<<<NBLK3, 256, 0, stream>>>(y2, batch, pW2, g2b, xm2, x, musum, sqsum,
                                  gamma, beta, out);
}